// Round 1
// baseline (465.746 us; speedup 1.0000x reference)
//
#include <hip/hip_runtime.h>
#include <math.h>

#define SS 8
#define NN 32
#define DD 64
#define NP 496   // 32*31/2

__device__ __forceinline__ float wrap_pi(float d) {
    // arctan2(sin d, cos d) == principal angle of d
    return d - 6.28318530717958647692f * rintf(d * 0.15915494309189533577f);
}
__device__ __forceinline__ float gelu_exact(float x) {
    return 0.5f * x * (1.0f + erff(x * 0.70710678118654752440f));
}
__device__ __forceinline__ float sigmoidf_(float x) {
    return 1.0f / (1.0f + __expf(-x));
}

__global__ __launch_bounds__(256) void edge_kernel(
    const float* __restrict__ cel,    // (B,S,N,D)
    const float* __restrict__ theta,  // (B,N)
    const float* __restrict__ phi,
    const float* __restrict__ vel,
    const float* __restrict__ rad,
    const float* __restrict__ lon,
    const float* __restrict__ W1,     // (134,64)
    const float* __restrict__ b1,     // (64)
    const float* __restrict__ W2,     // (64,32)
    const float* __restrict__ b2,     // (32)
    const float* __restrict__ W3,     // (32)
    const float* __restrict__ b3,     // (1)
    const float* __restrict__ pw,     // (6)
    float* __restrict__ out)          // (B,N,N)
{
    __shared__ float sW1[128 * 64];   // rows 0..127 of W1 (fi|fj halves)
    __shared__ float sW1s[6 * 64];    // rows 128..133 (scal features)
    __shared__ float sW2[64 * 32];
    __shared__ float sFe[32 * 64];    // feats = cel[:, -1]
    __shared__ float sAi[32 * 65];    // fi @ W1[0:64]   (+1 pad: bank spread)
    __shared__ float sBj[32 * 65];    // fj @ W1[64:128]
    __shared__ float sTh[32], sPh[32], sVe[32], sRa[32], sLo[32];
    __shared__ float sB1[64], sB2v[32], sW3v[32];
    __shared__ float sPW[6];
    __shared__ float sB3;
    __shared__ unsigned char sI[NP], sJ[NP];
    __shared__ float sAdj[32 * 32];

    const int b = blockIdx.x;
    const int t = threadIdx.x;

    // ---- stage weights / inputs into LDS ----
    for (int idx = t; idx < 134 * 64; idx += 256) {
        float v = W1[idx];
        if (idx < 128 * 64) sW1[idx] = v;
        else                sW1s[idx - 128 * 64] = v;
    }
    for (int idx = t; idx < 64 * 32; idx += 256) sW2[idx] = W2[idx];
    {
        const float* fsrc = cel + ((size_t)b * SS + (SS - 1)) * (NN * DD);
        for (int idx = t; idx < NN * DD; idx += 256) sFe[idx] = fsrc[idx];
    }
    if (t < 32) {
        sTh[t]  = theta[b * NN + t];
        sPh[t]  = phi[b * NN + t];
        sVe[t]  = vel[b * NN + t];
        sRa[t]  = rad[b * NN + t];
        sLo[t]  = lon[b * NN + t];
        sW3v[t] = W3[t];
        sB2v[t] = b2[t];
    } else if (t < 96) {
        sB1[t - 32] = b1[t - 32];
    } else if (t < 102) {
        sPW[t - 96] = pw[t - 96];
    } else if (t == 102) {
        sB3 = b3[0];
    }
    // triu pair table: row i owns 31-i pairs starting at offset 31i - i(i-1)/2
    if (t < 31) {
        int off = t * 31 - (t * (t - 1)) / 2;
        for (int j = t + 1; j < 32; ++j) {
            sI[off] = (unsigned char)t;
            sJ[off] = (unsigned char)j;
            ++off;
        }
    }
    for (int idx = t; idx < 1024; idx += 256) sAdj[idx] = 0.0f;  // diagonal stays 0
    __syncthreads();

    // ---- Phase A: per-node projections Ai = f@W1[0:64], Bj = f@W1[64:128] ----
    {
        const int col = t & 63;
        const int w   = t >> 6;
        for (int n = w; n < 32; n += 4) {
            float a = 0.0f, bb = 0.0f;
            #pragma unroll 8
            for (int k = 0; k < 64; ++k) {
                float f = sFe[n * 64 + k];           // wave-uniform broadcast
                a  += f * sW1[k * 64 + col];         // lane==col: conflict-free
                bb += f * sW1[(k + 64) * 64 + col];
            }
            sAi[n * 65 + col] = a;
            sBj[n * 65 + col] = bb;
        }
    }
    __syncthreads();

    // ---- Phase B: one pair per thread (496 pairs, 2 rounds) ----
    const float4* w2v = (const float4*)sW2;
    for (int p = t; p < NP; p += 256) {
        const int i = sI[p], j = sJ[p];
        const float td = wrap_pi(sTh[i] - sTh[j]);
        const float pd = wrap_pi(sPh[i] - sPh[j]);
        const float vd = sVe[i] - sVe[j];
        const float rr = sRa[i] / (sRa[j] + 1e-8f);
        const float ld = wrap_pi(sLo[i] - sLo[j]);
        const float pr = cosf(td) * cosf(pd);

        float acc[32];
        #pragma unroll
        for (int c = 0; c < 32; ++c) acc[c] = sB2v[c];

        // fused: h1[k] = gelu(Ai[i][k] + Bj[j][k] + scal@W1s[:,k] + b1[k]),
        // immediately folded into h2 accumulators (h1 never stored)
        for (int k = 0; k < 64; ++k) {
            float x = sAi[i * 65 + k] + sBj[j * 65 + k] + sB1[k]
                    + td * sW1s[0 * 64 + k] + pd * sW1s[1 * 64 + k]
                    + vd * sW1s[2 * 64 + k] + rr * sW1s[3 * 64 + k]
                    + ld * sW1s[4 * 64 + k] + pr * sW1s[5 * 64 + k];
            const float h = gelu_exact(x);
            #pragma unroll
            for (int c8 = 0; c8 < 8; ++c8) {      // W2 row k: wave-uniform float4 reads
                const float4 wv = w2v[k * 8 + c8];
                acc[c8 * 4 + 0] += h * wv.x;
                acc[c8 * 4 + 1] += h * wv.y;
                acc[c8 * 4 + 2] += h * wv.z;
                acc[c8 * 4 + 3] += h * wv.w;
            }
        }
        float h3 = sB3;
        #pragma unroll
        for (int c = 0; c < 32; ++c) h3 += gelu_exact(acc[c]) * sW3v[c];
        const float edge = sigmoidf_(h3);
        const float pf = fabsf(td) * sPW[0] + fabsf(pd) * sPW[1]
                       + fabsf(vd) * sPW[2] + fabsf(rr - 1.0f) * sPW[3]
                       + fabsf(ld) * sPW[4] + fabsf(pr) * sPW[5];
        const float fe = edge * sigmoidf_(pf);
        sAdj[i * 32 + j] = fe;
        sAdj[j * 32 + i] = fe;
    }
    __syncthreads();

    // ---- coalesced tile writeback ----
    float* dst = out + (size_t)b * 1024;
    for (int idx = t; idx < 1024; idx += 256) dst[idx] = sAdj[idx];
}

extern "C" void kernel_launch(void* const* d_in, const int* in_sizes, int n_in,
                              void* d_out, int out_size, void* d_ws, size_t ws_size,
                              hipStream_t stream) {
    const float* cel   = (const float*)d_in[0];
    const float* theta = (const float*)d_in[1];
    const float* phi   = (const float*)d_in[2];
    const float* vel   = (const float*)d_in[3];
    const float* rad   = (const float*)d_in[4];
    const float* lon   = (const float*)d_in[5];
    const float* W1    = (const float*)d_in[6];
    const float* b1    = (const float*)d_in[7];
    const float* W2    = (const float*)d_in[8];
    const float* b2    = (const float*)d_in[9];
    const float* W3    = (const float*)d_in[10];
    const float* b3    = (const float*)d_in[11];
    const float* pw    = (const float*)d_in[12];
    float* out = (float*)d_out;

    const int B = in_sizes[1] / NN;  // theta is (B,N)
    edge_kernel<<<B, 256, 0, stream>>>(cel, theta, phi, vel, rad, lon,
                                       W1, b1, W2, b2, W3, b3, pw, out);
}

// Round 2
// 325.615 us; speedup vs baseline: 1.4304x; 1.4304x over previous
//
#include <hip/hip_runtime.h>
#include <math.h>

#define SS 8
#define NN 32
#define DD 64
#define NP 496   // 32*31/2
#define LDA 68   // padded row stride (floats) for sAi/sBj: 16B-aligned, odd bank phase

__device__ __forceinline__ float wrap_pi(float d) {
    // arctan2(sin d, cos d) == principal angle of d
    return fmaf(-6.28318530717958647692f, rintf(d * 0.15915494309189533577f), d);
}
// Abramowitz-Stegun 7.1.26 minimax erf, max abs err 1.5e-7, branch-free (~12 VALU)
__device__ __forceinline__ float erf_fast(float x) {
    float ax = fabsf(x);
    float t = __builtin_amdgcn_rcpf(fmaf(0.3275911f, ax, 1.0f));
    float p = t * fmaf(t, fmaf(t, fmaf(t, fmaf(t, 1.061405429f, -1.453152027f),
                                        1.421413741f), -0.284496736f), 0.254829592f);
    float e = __expf(-ax * ax);
    float r = fmaf(-p, e, 1.0f);
    return copysignf(r, x);
}
__device__ __forceinline__ float gelu_fast(float x) {
    return 0.5f * x * (1.0f + erf_fast(x * 0.70710678118654752440f));
}
__device__ __forceinline__ float sigmoid_(float x) {
    return 1.0f / (1.0f + __expf(-x));
}

__global__ __launch_bounds__(256, 4) void edge_kernel(
    const float* __restrict__ cel,    // (B,S,N,D)
    const float* __restrict__ theta,  // (B,N)
    const float* __restrict__ phi,
    const float* __restrict__ vel,
    const float* __restrict__ rad,
    const float* __restrict__ lon,
    const float* __restrict__ W1,     // (134,64)
    const float* __restrict__ b1,     // (64)
    const float* __restrict__ W2,     // (64,32)
    const float* __restrict__ b2,     // (32)
    const float* __restrict__ W3,     // (32)
    const float* __restrict__ b3,     // (1)
    const float* __restrict__ pw,     // (6)
    float* __restrict__ out)          // (B,N,N)
{
    __shared__ float sAi[NN * LDA];   // fi @ W1[0:64] + b1  (per node)
    __shared__ float sBj[NN * LDA];   // fj @ W1[64:128]     (per node)
    __shared__ float sAdj[NN * NN];
    __shared__ float sTh[NN], sPh[NN], sVe[NN], sRa[NN], sLo[NN];
    __shared__ unsigned char sI[NP], sJ[NP];

    const int b = blockIdx.x;
    const int t = threadIdx.x;

    if (t < NN) {
        sTh[t] = theta[b * NN + t];
        sPh[t] = phi[b * NN + t];
        sVe[t] = vel[b * NN + t];
        sRa[t] = rad[b * NN + t];
        sLo[t] = lon[b * NN + t];
    }
    // triu pair table: row i owns 31-i pairs starting at offset 31i - i(i-1)/2
    if (t < 31) {
        int off = t * 31 - (t * (t - 1)) / 2;
        for (int j = t + 1; j < 32; ++j) {
            sI[off] = (unsigned char)t;
            sJ[off] = (unsigned char)j;
            ++off;
        }
    }
    for (int idx = t; idx < 1024; idx += 256) sAdj[idx] = 0.0f;  // diagonal stays 0

    // ---- Phase A: per-node projections. col = lane (coalesced W1 loads from
    // L1/L2); node index derived from wave id, pinned to SGPR so the feats
    // loads are provably wave-uniform -> s_load on the scalar pipe.
    {
        const int col = t & 63;
        const int w   = __builtin_amdgcn_readfirstlane(t >> 6);
        const float* fbase = cel + ((size_t)b * SS + (SS - 1)) * (NN * DD);
        float a[8], bb[8];
        #pragma unroll
        for (int m = 0; m < 8; ++m) { a[m] = 0.0f; bb[m] = 0.0f; }
        for (int k = 0; k < 64; ++k) {
            const float w1a = W1[k * 64 + col];          // vector, coalesced
            const float w1b = W1[(k + 64) * 64 + col];
            #pragma unroll
            for (int m = 0; m < 8; ++m) {
                const float f = fbase[(w + 4 * m) * 64 + k];   // scalar load
                a[m]  = fmaf(f, w1a, a[m]);
                bb[m] = fmaf(f, w1b, bb[m]);
            }
        }
        const float b1c = b1[col];
        #pragma unroll
        for (int m = 0; m < 8; ++m) {
            sAi[(w + 4 * m) * LDA + col] = a[m] + b1c;   // fold b1 here
            sBj[(w + 4 * m) * LDA + col] = bb[m];
        }
    }
    __syncthreads();

    // ---- Phase B: one pair per thread. All weight reads are wave-uniform
    // (indices are loop counters) -> scalar loads; FMAs take SGPR operands.
    const float* W1s = W1 + 128 * 64;   // rows 128..133 (scal features)
    for (int p = t; p < NP; p += 256) {
        const int i = sI[p], j = sJ[p];
        const float td = wrap_pi(sTh[i] - sTh[j]);
        const float pd = wrap_pi(sPh[i] - sPh[j]);
        const float vd = sVe[i] - sVe[j];
        const float rr = sRa[i] / (sRa[j] + 1e-8f);
        const float ld = wrap_pi(sLo[i] - sLo[j]);
        const float pr = __cosf(td) * __cosf(pd);

        float acc[32];
        #pragma unroll
        for (int c = 0; c < 32; ++c) acc[c] = b2[c];     // scalar loads

        const float* Arow = &sAi[i * LDA];
        const float* Brow = &sBj[j * LDA];
        for (int kq = 0; kq < 16; ++kq) {
            const float4 av = *(const float4*)(Arow + 4 * kq);   // ds_read_b128
            const float4 bv = *(const float4*)(Brow + 4 * kq);
            const float4 s0 = *(const float4*)(W1s + 0 * 64 + 4 * kq);  // s_load
            const float4 s1 = *(const float4*)(W1s + 1 * 64 + 4 * kq);
            const float4 s2 = *(const float4*)(W1s + 2 * 64 + 4 * kq);
            const float4 s3 = *(const float4*)(W1s + 3 * 64 + 4 * kq);
            const float4 s4 = *(const float4*)(W1s + 4 * 64 + 4 * kq);
            const float4 s5 = *(const float4*)(W1s + 5 * 64 + 4 * kq);
            const float* avp = (const float*)&av;
            const float* bvp = (const float*)&bv;
            const float* s0p = (const float*)&s0;
            const float* s1p = (const float*)&s1;
            const float* s2p = (const float*)&s2;
            const float* s3p = (const float*)&s3;
            const float* s4p = (const float*)&s4;
            const float* s5p = (const float*)&s5;
            #pragma unroll
            for (int kk = 0; kk < 4; ++kk) {
                float x = avp[kk] + bvp[kk];
                x = fmaf(td, s0p[kk], x);
                x = fmaf(pd, s1p[kk], x);
                x = fmaf(vd, s2p[kk], x);
                x = fmaf(rr, s3p[kk], x);
                x = fmaf(ld, s4p[kk], x);
                x = fmaf(pr, s5p[kk], x);
                const float h = gelu_fast(x);
                const float4* w2r = (const float4*)(W2 + (4 * kq + kk) * 32);
                #pragma unroll
                for (int c8 = 0; c8 < 8; ++c8) {
                    const float4 wv = w2r[c8];           // s_load_dwordx4
                    acc[4 * c8 + 0] = fmaf(h, wv.x, acc[4 * c8 + 0]);
                    acc[4 * c8 + 1] = fmaf(h, wv.y, acc[4 * c8 + 1]);
                    acc[4 * c8 + 2] = fmaf(h, wv.z, acc[4 * c8 + 2]);
                    acc[4 * c8 + 3] = fmaf(h, wv.w, acc[4 * c8 + 3]);
                }
            }
        }
        float h3 = b3[0];
        #pragma unroll
        for (int c = 0; c < 32; ++c) h3 = fmaf(gelu_fast(acc[c]), W3[c], h3);
        const float edge = sigmoid_(h3);
        const float pf = fabsf(td) * pw[0] + fabsf(pd) * pw[1]
                       + fabsf(vd) * pw[2] + fabsf(rr - 1.0f) * pw[3]
                       + fabsf(ld) * pw[4] + fabsf(pr) * pw[5];
        const float fe = edge * sigmoid_(pf);
        sAdj[i * 32 + j] = fe;
        sAdj[j * 32 + i] = fe;
    }
    __syncthreads();

    // ---- coalesced tile writeback ----
    float* dst = out + (size_t)b * 1024;
    for (int idx = t; idx < 1024; idx += 256) dst[idx] = sAdj[idx];
}

extern "C" void kernel_launch(void* const* d_in, const int* in_sizes, int n_in,
                              void* d_out, int out_size, void* d_ws, size_t ws_size,
                              hipStream_t stream) {
    const float* cel   = (const float*)d_in[0];
    const float* theta = (const float*)d_in[1];
    const float* phi   = (const float*)d_in[2];
    const float* vel   = (const float*)d_in[3];
    const float* rad   = (const float*)d_in[4];
    const float* lon   = (const float*)d_in[5];
    const float* W1    = (const float*)d_in[6];
    const float* b1    = (const float*)d_in[7];
    const float* W2    = (const float*)d_in[8];
    const float* b2    = (const float*)d_in[9];
    const float* W3    = (const float*)d_in[10];
    const float* b3    = (const float*)d_in[11];
    const float* pw    = (const float*)d_in[12];
    float* out = (float*)d_out;

    const int B = in_sizes[1] / NN;  // theta is (B,N)
    edge_kernel<<<B, 256, 0, stream>>>(cel, theta, phi, vel, rad, lon,
                                       W1, b1, W2, b2, W3, b3, pw, out);
}

// Round 3
// 318.196 us; speedup vs baseline: 1.4637x; 1.0233x over previous
//
#include <hip/hip_runtime.h>
#include <math.h>

#define SS 8
#define NN 32
#define DD 64
#define NP 496   // 32*31/2
#define LDA 68   // padded row stride (floats) for sAi/sBj; 272B = odd multiple of 16B

typedef short v8s __attribute__((ext_vector_type(8)));   // 8 bf16 (4 VGPRs)
typedef float v4f __attribute__((ext_vector_type(4)));   // MFMA C/D frag

__device__ __forceinline__ float wrap_pi(float d) {
    return fmaf(-6.28318530717958647692f, rintf(d * 0.15915494309189533577f), d);
}
// A&S 7.1.26 minimax erf, max abs err 1.5e-7, branch-free
__device__ __forceinline__ float erf_fast(float x) {
    float ax = fabsf(x);
    float t = __builtin_amdgcn_rcpf(fmaf(0.3275911f, ax, 1.0f));
    float p = t * fmaf(t, fmaf(t, fmaf(t, fmaf(t, 1.061405429f, -1.453152027f),
                                        1.421413741f), -0.284496736f), 0.254829592f);
    float e = __expf(-ax * ax);
    float r = fmaf(-p, e, 1.0f);
    return copysignf(r, x);
}
__device__ __forceinline__ float gelu_fast(float x) {
    return 0.5f * x * (1.0f + erf_fast(x * 0.70710678118654752440f));
}
__device__ __forceinline__ float sigmoid_(float x) {
    return 1.0f / (1.0f + __expf(-x));
}
// round-to-nearest-even fp32 -> bf16 pair, packed (lo = even element)
__device__ __forceinline__ unsigned int pack_bf16_rne(float x0, float x1) {
    unsigned int u0 = __float_as_uint(x0);
    unsigned int u1 = __float_as_uint(x1);
    u0 = u0 + 0x7fffu + ((u0 >> 16) & 1u);
    u1 = u1 + 0x7fffu + ((u1 >> 16) & 1u);
    return (u0 >> 16) | (u1 & 0xffff0000u);
}

__global__ __launch_bounds__(256, 2) void edge_kernel(
    const float* __restrict__ cel,    // (B,S,N,D)
    const float* __restrict__ theta,  // (B,N)
    const float* __restrict__ phi,
    const float* __restrict__ vel,
    const float* __restrict__ rad,
    const float* __restrict__ lon,
    const float* __restrict__ W1,     // (134,64)
    const float* __restrict__ b1,     // (64)
    const float* __restrict__ W2,     // (64,32)
    const float* __restrict__ b2,     // (32)
    const float* __restrict__ W3,     // (32)
    const float* __restrict__ b3,     // (1)
    const float* __restrict__ pw,     // (6)
    float* __restrict__ out)          // (B,N,N)
{
    __shared__ __align__(16) float sAi[NN * LDA];   // fi@W1[0:64] + b1
    __shared__ __align__(16) float sBj[NN * LDA];   // fj@W1[64:128]
    __shared__ __align__(16) float sW1s[6 * 64];    // W1 rows 128..133
    __shared__ __align__(16) float sScal[6][512];   // per-pair td,pd,vd,rr,ld,pr
    __shared__ float sGate[512];
    __shared__ float sTh[NN], sPh[NN], sVe[NN], sRa[NN], sLo[NN];
    __shared__ unsigned char sI[512], sJ[512];
    __shared__ uint4 sW2frag[256];     // B-frags: slot (nt*2+ks)*64 + lane
    __shared__ uint4 sH1frag[1024];    // A-frags for one 128-pair chunk
    __shared__ float sAdj[1024];

    const int b = blockIdx.x;
    const int t = threadIdx.x;

    // ================= step 1: staging / one-time prep =================
    if (t < NN) {
        sTh[t] = theta[b * NN + t];
        sPh[t] = phi[b * NN + t];
        sVe[t] = vel[b * NN + t];
        sRa[t] = rad[b * NN + t];
        sLo[t] = lon[b * NN + t];
    }
    if (t < 31) {  // triu pair table
        int off = t * 31 - (t * (t - 1)) / 2;
        for (int j = t + 1; j < 32; ++j) {
            sI[off] = (unsigned char)t;
            sJ[off] = (unsigned char)j;
            ++off;
        }
    }
    for (int idx = t; idx < 1024; idx += 256) sAdj[idx] = 0.0f;
    for (int idx = t; idx < 384; idx += 256) sW1s[idx] = W1[128 * 64 + idx];
    {   // W2 -> bf16 B-fragment layout: lane provides B[k=ks*32+ql*8+j][n=nt*16+ml]
        const int lane = t & 63, nt = t >> 7, ks = (t >> 6) & 1;
        const int ml = lane & 15, ql = lane >> 4;
        const int kb = ks * 32 + ql * 8, col = nt * 16 + ml;
        uint4 pk;
        pk.x = pack_bf16_rne(W2[(kb + 0) * 32 + col], W2[(kb + 1) * 32 + col]);
        pk.y = pack_bf16_rne(W2[(kb + 2) * 32 + col], W2[(kb + 3) * 32 + col]);
        pk.z = pack_bf16_rne(W2[(kb + 4) * 32 + col], W2[(kb + 5) * 32 + col]);
        pk.w = pack_bf16_rne(W2[(kb + 6) * 32 + col], W2[(kb + 7) * 32 + col]);
        sW2frag[t] = pk;
    }
    __syncthreads();

    // ================= step 2: per-pair scalars + gate =================
    for (int p = t; p < NP; p += 256) {
        const int i = sI[p], j = sJ[p];
        const float td = wrap_pi(sTh[i] - sTh[j]);
        const float pd = wrap_pi(sPh[i] - sPh[j]);
        const float vd = sVe[i] - sVe[j];
        const float rr = sRa[i] / (sRa[j] + 1e-8f);
        const float ld = wrap_pi(sLo[i] - sLo[j]);
        const float pr = __cosf(td) * __cosf(pd);
        sScal[0][p] = td; sScal[1][p] = pd; sScal[2][p] = vd;
        sScal[3][p] = rr; sScal[4][p] = ld; sScal[5][p] = pr;
        const float pf = fabsf(td) * pw[0] + fabsf(pd) * pw[1]
                       + fabsf(vd) * pw[2] + fabsf(rr - 1.0f) * pw[3]
                       + fabsf(ld) * pw[4] + fabsf(pr) * pw[5];
        sGate[p] = sigmoid_(pf);
    }

    // ================= phase A: node projections (fp32, VALU) ==========
    {
        const int col = t & 63;
        const int w   = __builtin_amdgcn_readfirstlane(t >> 6);
        const float* fbase = cel + ((size_t)b * SS + (SS - 1)) * (NN * DD);
        float a[8], bb[8];
        #pragma unroll
        for (int m = 0; m < 8; ++m) { a[m] = 0.0f; bb[m] = 0.0f; }
        for (int k = 0; k < 64; ++k) {
            const float w1a = W1[k * 64 + col];
            const float w1b = W1[(k + 64) * 64 + col];
            #pragma unroll
            for (int m = 0; m < 8; ++m) {
                const float f = fbase[(w + 4 * m) * 64 + k];   // scalar load
                a[m]  = fmaf(f, w1a, a[m]);
                bb[m] = fmaf(f, w1b, bb[m]);
            }
        }
        const float b1c = b1[col];
        #pragma unroll
        for (int m = 0; m < 8; ++m) {
            sAi[(w + 4 * m) * LDA + col] = a[m] + b1c;
            sBj[(w + 4 * m) * LDA + col] = bb[m];
        }
    }
    __syncthreads();

    // ============ hoisted per-thread constants for the chunk loop ======
    const int qT  = (t >> 4) & 3;          // frag k-quad this thread produces
    const int ksT = (t >> 6) & 1;          // frag k-step
    const int mT  = t & 15;                // frag row-within-tile
    const int k0  = ksT * 32 + qT * 8;
    float w1r[6][8];                        // W1s slice this thread needs, in VGPRs
    #pragma unroll
    for (int s = 0; s < 6; ++s) {
        const float4 u0 = *(const float4*)&sW1s[s * 64 + k0];
        const float4 u1 = *(const float4*)&sW1s[s * 64 + k0 + 4];
        w1r[s][0] = u0.x; w1r[s][1] = u0.y; w1r[s][2] = u0.z; w1r[s][3] = u0.w;
        w1r[s][4] = u1.x; w1r[s][5] = u1.y; w1r[s][6] = u1.z; w1r[s][7] = u1.w;
    }
    const int lane = t & 63, ml = lane & 15, ql = lane >> 4;
    const int wv = t >> 6;
    const float b2v0 = b2[ml],      b2v1 = b2[16 + ml];
    const float w3v0 = W3[ml],      w3v1 = W3[16 + ml];
    const float b3s  = b3[0];
    const v8s bf00 = *(const v8s*)&sW2frag[(0 * 2 + 0) * 64 + lane];  // nt0,ks0
    const v8s bf01 = *(const v8s*)&sW2frag[(0 * 2 + 1) * 64 + lane];  // nt0,ks1
    const v8s bf10 = *(const v8s*)&sW2frag[(1 * 2 + 0) * 64 + lane];  // nt1,ks0
    const v8s bf11 = *(const v8s*)&sW2frag[(1 * 2 + 1) * 64 + lane];  // nt1,ks1

    // ================= chunk loop: 4 x 128 pairs =======================
    for (int chunk = 0; chunk < 4; ++chunk) {
        const int nmt = (chunk == 3) ? 7 : 8;   // 496 = 3*128 + 7*16

        // ---- stage A: h1 = gelu(x1) in bf16 A-frag order ----
        #pragma unroll
        for (int r = 0; r < 4; ++r) {
            const int mt = 2 * r + (t >> 7);
            if (mt >= nmt) continue;            // wave-uniform trim (chunk 3)
            const int p = chunk * 128 + mt * 16 + mT;
            const int i = sI[p], j = sJ[p];
            const float* Ar = &sAi[i * LDA + k0];
            const float* Br = &sBj[j * LDA + k0];
            const float4 a0 = *(const float4*)Ar;
            const float4 a1 = *(const float4*)(Ar + 4);
            const float4 c0 = *(const float4*)Br;
            const float4 c1 = *(const float4*)(Br + 4);
            float sc[6];
            #pragma unroll
            for (int s = 0; s < 6; ++s) sc[s] = sScal[s][p];
            float x[8] = {a0.x + c0.x, a0.y + c0.y, a0.z + c0.z, a0.w + c0.w,
                          a1.x + c1.x, a1.y + c1.y, a1.z + c1.z, a1.w + c1.w};
            #pragma unroll
            for (int jj = 0; jj < 8; ++jj) {
                #pragma unroll
                for (int s = 0; s < 6; ++s)
                    x[jj] = fmaf(sc[s], w1r[s][jj], x[jj]);
                x[jj] = gelu_fast(x[jj]);
            }
            uint4 pk;
            pk.x = pack_bf16_rne(x[0], x[1]);
            pk.y = pack_bf16_rne(x[2], x[3]);
            pk.z = pack_bf16_rne(x[4], x[5]);
            pk.w = pack_bf16_rne(x[6], x[7]);
            sH1frag[(mt * 2 + ksT) * 64 + qT * 16 + mT] = pk;  // = ..*64 + (t&63)
        }
        __syncthreads();

        // ---- stage B/C: MFMA GEMM + gelu + W3-dot + gate + scatter ----
        #pragma unroll
        for (int half = 0; half < 2; ++half) {
            const int mtl = wv + 4 * half;
            if (mtl < nmt) {
                v4f acc0 = {b2v0, b2v0, b2v0, b2v0};
                v4f acc1 = {b2v1, b2v1, b2v1, b2v1};
                const v8s a0f = *(const v8s*)&sH1frag[(mtl * 2 + 0) * 64 + lane];
                const v8s a1f = *(const v8s*)&sH1frag[(mtl * 2 + 1) * 64 + lane];
                acc0 = __builtin_amdgcn_mfma_f32_16x16x32_bf16(a0f, bf00, acc0, 0, 0, 0);
                acc0 = __builtin_amdgcn_mfma_f32_16x16x32_bf16(a1f, bf01, acc0, 0, 0, 0);
                acc1 = __builtin_amdgcn_mfma_f32_16x16x32_bf16(a0f, bf10, acc1, 0, 0, 0);
                acc1 = __builtin_amdgcn_mfma_f32_16x16x32_bf16(a1f, bf11, acc1, 0, 0, 0);
                float c[4];
                #pragma unroll
                for (int r = 0; r < 4; ++r)
                    c[r] = fmaf(gelu_fast(acc0[r]), w3v0, gelu_fast(acc1[r]) * w3v1);
                #pragma unroll
                for (int d = 1; d < 16; d <<= 1) {
                    #pragma unroll
                    for (int r = 0; r < 4; ++r)
                        c[r] += __shfl_xor(c[r], d, 16);   // col-sum per row
                }
                const int pbase = chunk * 128 + mtl * 16 + ql * 4;
                #pragma unroll
                for (int r = 0; r < 4; ++r) {
                    const float edge = sigmoid_(c[r] + b3s);
                    const float fe = edge * sGate[pbase + r];
                    if (ml == 0) {
                        const int pi = sI[pbase + r], pj = sJ[pbase + r];
                        sAdj[pi * 32 + pj] = fe;
                        sAdj[pj * 32 + pi] = fe;
                    }
                }
            }
        }
        __syncthreads();
    }

    // ================= coalesced tile writeback ========================
    float* dst = out + (size_t)b * 1024;
    for (int idx = t; idx < 1024; idx += 256) dst[idx] = sAdj[idx];
}

extern "C" void kernel_launch(void* const* d_in, const int* in_sizes, int n_in,
                              void* d_out, int out_size, void* d_ws, size_t ws_size,
                              hipStream_t stream) {
    const float* cel   = (const float*)d_in[0];
    const float* theta = (const float*)d_in[1];
    const float* phi   = (const float*)d_in[2];
    const float* vel   = (const float*)d_in[3];
    const float* rad   = (const float*)d_in[4];
    const float* lon   = (const float*)d_in[5];
    const float* W1    = (const float*)d_in[6];
    const float* b1    = (const float*)d_in[7];
    const float* W2    = (const float*)d_in[8];
    const float* b2    = (const float*)d_in[9];
    const float* W3    = (const float*)d_in[10];
    const float* b3    = (const float*)d_in[11];
    const float* pw    = (const float*)d_in[12];
    float* out = (float*)d_out;

    const int B = in_sizes[1] / NN;  // theta is (B,N)
    edge_kernel<<<B, 256, 0, stream>>>(cel, theta, phi, vel, rad, lon,
                                       W1, b1, W2, b2, W3, b3, pw, out);
}

// Round 5
// 295.968 us; speedup vs baseline: 1.5736x; 1.0751x over previous
//
#include <hip/hip_runtime.h>
#include <math.h>

#define SS 8
#define NN 32
#define DD 64
#define NP 496   // 32*31/2
#define LDA 68   // padded row stride (floats) for sAi/sBj; 272B (16B-aligned)

typedef short v8s __attribute__((ext_vector_type(8)));   // 8 bf16 (4 VGPRs)
typedef float v4f __attribute__((ext_vector_type(4)));   // MFMA C/D frag

union FragU { uint4 u; v8s s; };

__device__ __forceinline__ float wrap_pi(float d) {
    return fmaf(-6.28318530717958647692f, rintf(d * 0.15915494309189533577f), d);
}
// A&S 7.1.26 minimax erf, max abs err 1.5e-7, branch-free
__device__ __forceinline__ float erf_fast(float x) {
    float ax = fabsf(x);
    float t = __builtin_amdgcn_rcpf(fmaf(0.3275911f, ax, 1.0f));
    float p = t * fmaf(t, fmaf(t, fmaf(t, fmaf(t, 1.061405429f, -1.453152027f),
                                        1.421413741f), -0.284496736f), 0.254829592f);
    float e = __expf(-ax * ax);
    float r = fmaf(-p, e, 1.0f);
    return copysignf(r, x);
}
__device__ __forceinline__ float gelu_fast(float x) {
    return 0.5f * x * (1.0f + erf_fast(x * 0.70710678118654752440f));
}
__device__ __forceinline__ float sigmoid_(float x) {
    return 1.0f / (1.0f + __expf(-x));
}
// round-to-nearest-even fp32 -> bf16 pair, packed (lo = even element)
__device__ __forceinline__ unsigned int pack_bf16_rne(float x0, float x1) {
    unsigned int u0 = __float_as_uint(x0);
    unsigned int u1 = __float_as_uint(x1);
    u0 = u0 + 0x7fffu + ((u0 >> 16) & 1u);
    u1 = u1 + 0x7fffu + ((u1 >> 16) & 1u);
    return (u0 >> 16) | (u1 & 0xffff0000u);
}
// Sum across each 16-lane DPP row using row_ror (rotate) steps 8,4,2,1.
// Rotation-based butterfly: after ror:8 the value sequence has period 8,
// after ror:4 period 4, ... after ror:1 EVERY lane holds the full row sum —
// correct regardless of the hardware's rotate-direction convention, and no
// lane is ever out-of-range (bound_ctrl/old never used). Pure VALU pipe.
__device__ __forceinline__ float row_reduce16(float x) {
    int v;
    v = __builtin_amdgcn_update_dpp(0, __float_as_int(x), 0x128, 0xf, 0xf, false); // row_ror:8
    x += __int_as_float(v);
    v = __builtin_amdgcn_update_dpp(0, __float_as_int(x), 0x124, 0xf, 0xf, false); // row_ror:4
    x += __int_as_float(v);
    v = __builtin_amdgcn_update_dpp(0, __float_as_int(x), 0x122, 0xf, 0xf, false); // row_ror:2
    x += __int_as_float(v);
    v = __builtin_amdgcn_update_dpp(0, __float_as_int(x), 0x121, 0xf, 0xf, false); // row_ror:1
    x += __int_as_float(v);
    return x;
}
__device__ __forceinline__ uint4 build_w2_frag(const float* __restrict__ W2,
                                               int kb, int col) {
    uint4 pk;
    pk.x = pack_bf16_rne(W2[(kb + 0) * 32 + col], W2[(kb + 1) * 32 + col]);
    pk.y = pack_bf16_rne(W2[(kb + 2) * 32 + col], W2[(kb + 3) * 32 + col]);
    pk.z = pack_bf16_rne(W2[(kb + 4) * 32 + col], W2[(kb + 5) * 32 + col]);
    pk.w = pack_bf16_rne(W2[(kb + 6) * 32 + col], W2[(kb + 7) * 32 + col]);
    return pk;
}

__global__ __launch_bounds__(256, 4) void edge_kernel(
    const float* __restrict__ cel,    // (B,S,N,D)
    const float* __restrict__ theta,  // (B,N)
    const float* __restrict__ phi,
    const float* __restrict__ vel,
    const float* __restrict__ rad,
    const float* __restrict__ lon,
    const float* __restrict__ W1,     // (134,64)
    const float* __restrict__ b1,     // (64)
    const float* __restrict__ W2,     // (64,32)
    const float* __restrict__ b2,     // (32)
    const float* __restrict__ W3,     // (32)
    const float* __restrict__ b3,     // (1)
    const float* __restrict__ pw,     // (6)
    float* __restrict__ out)          // (B,N,N)
{
    __shared__ __align__(16) float sAi[NN * LDA];    // fi@W1[0:64] + b1
    __shared__ __align__(16) float sBj[NN * LDA];    // fj@W1[64:128]
    __shared__ __align__(16) float sW1s[6 * 64];     // W1 rows 128..133
    __shared__ float sScal[6][512];                  // per-pair td,pd,vd,rr,ld,pr
    __shared__ float sGate[512];
    __shared__ float sTh[NN], sPh[NN], sVe[NN], sRa[NN], sLo[NN];
    __shared__ unsigned char sI[512], sJ[512];
    __shared__ float sAdj[1024];

    const int b = blockIdx.x;
    const int t = threadIdx.x;
    const int ml = t & 15;            // frag row-within-tile / C col
    const int ql = (t >> 4) & 3;      // frag k-quad / C row-quad (== lane>>4)
    const int wv = t >> 6;            // wave id
    const int kA = ql * 8;            // this lane's ks0 k-base

    // ---- B-fragments of W2 straight from global (per-thread, no LDS) ----
    FragU f00, f01, f10, f11;
    f00.u = build_w2_frag(W2, 0 * 32 + kA, 0 * 16 + ml);
    f01.u = build_w2_frag(W2, 1 * 32 + kA, 0 * 16 + ml);
    f10.u = build_w2_frag(W2, 0 * 32 + kA, 1 * 16 + ml);
    f11.u = build_w2_frag(W2, 1 * 32 + kA, 1 * 16 + ml);
    const float b2v0 = b2[ml], b2v1 = b2[16 + ml];
    const float w3v0 = W3[ml], w3v1 = W3[16 + ml];
    const float b3s  = b3[0];

    // ---- staging ----
    if (t < NN) {
        sTh[t] = theta[b * NN + t];
        sPh[t] = phi[b * NN + t];
        sVe[t] = vel[b * NN + t];
        sRa[t] = rad[b * NN + t];
        sLo[t] = lon[b * NN + t];
    }
    if (t < 31) {  // triu pair table
        int off = t * 31 - (t * (t - 1)) / 2;
        for (int j = t + 1; j < 32; ++j) {
            sI[off] = (unsigned char)t;
            sJ[off] = (unsigned char)j;
            ++off;
        }
    }
    for (int idx = t; idx < 1024; idx += 256) sAdj[idx] = 0.0f;
    for (int idx = t; idx < 384; idx += 256) sW1s[idx] = W1[128 * 64 + idx];
    __syncthreads();   // barrier 1

    // ---- per-pair scalars + gate ----
    for (int p = t; p < NP; p += 256) {
        const int i = sI[p], j = sJ[p];
        const float td = wrap_pi(sTh[i] - sTh[j]);
        const float pd = wrap_pi(sPh[i] - sPh[j]);
        const float vd = sVe[i] - sVe[j];
        const float rr = sRa[i] / (sRa[j] + 1e-8f);
        const float ld = wrap_pi(sLo[i] - sLo[j]);
        const float pr = __cosf(td) * __cosf(pd);
        sScal[0][p] = td; sScal[1][p] = pd; sScal[2][p] = vd;
        sScal[3][p] = rr; sScal[4][p] = ld; sScal[5][p] = pr;
        const float pf = fabsf(td) * pw[0] + fabsf(pd) * pw[1]
                       + fabsf(vd) * pw[2] + fabsf(rr - 1.0f) * pw[3]
                       + fabsf(ld) * pw[4] + fabsf(pr) * pw[5];
        sGate[p] = sigmoid_(pf);
    }

    // ---- phase A: node projections (fp32 VALU) ----
    {
        const int col = t & 63;
        const int w   = __builtin_amdgcn_readfirstlane(t >> 6);
        const float* fbase = cel + ((size_t)b * SS + (SS - 1)) * (NN * DD);
        float a[8], bb[8];
        #pragma unroll
        for (int m = 0; m < 8; ++m) { a[m] = 0.0f; bb[m] = 0.0f; }
        for (int k = 0; k < 64; ++k) {
            const float w1a = W1[k * 64 + col];
            const float w1b = W1[(k + 64) * 64 + col];
            #pragma unroll
            for (int m = 0; m < 8; ++m) {
                const float f = fbase[(w + 4 * m) * 64 + k];   // s_load
                a[m]  = fmaf(f, w1a, a[m]);
                bb[m] = fmaf(f, w1b, bb[m]);
            }
        }
        const float b1c = b1[col];
        #pragma unroll
        for (int m = 0; m < 8; ++m) {
            sAi[(w + 4 * m) * LDA + col] = a[m] + b1c;
            sBj[(w + 4 * m) * LDA + col] = bb[m];
        }
    }
    __syncthreads();   // barrier 2

    // ---- hoist this lane's ks0 slice of W1s (48 VGPRs, round-invariant) ----
    float w1r[6][8];
    #pragma unroll
    for (int s = 0; s < 6; ++s) {
        const float4 u0 = *(const float4*)&sW1s[s * 64 + kA];
        const float4 u1 = *(const float4*)&sW1s[s * 64 + kA + 4];
        w1r[s][0] = u0.x; w1r[s][1] = u0.y; w1r[s][2] = u0.z; w1r[s][3] = u0.w;
        w1r[s][4] = u1.x; w1r[s][5] = u1.y; w1r[s][6] = u1.z; w1r[s][7] = u1.w;
    }

    // ---- main loop: one 16-pair m-tile per wave-round, ZERO barriers ----
    for (int r = 0; r < 8; ++r) {
        const int mtl = r * 4 + wv;
        if (mtl >= 31) break;                    // wave-uniform
        const int p = mtl * 16 + ml;
        const int i = sI[p], j = sJ[p];
        float sc[6];
        #pragma unroll
        for (int s = 0; s < 6; ++s) sc[s] = sScal[s][p];
        const float* Ar = &sAi[i * LDA];
        const float* Br = &sBj[j * LDA];

        // ks0 half: k = kA..kA+7 (W1s slice from registers)
        FragU fa0, fa1;
        {
            const float4 p0 = *(const float4*)(Ar + kA);
            const float4 p1 = *(const float4*)(Ar + kA + 4);
            const float4 q0 = *(const float4*)(Br + kA);
            const float4 q1 = *(const float4*)(Br + kA + 4);
            float x[8] = {p0.x + q0.x, p0.y + q0.y, p0.z + q0.z, p0.w + q0.w,
                          p1.x + q1.x, p1.y + q1.y, p1.z + q1.z, p1.w + q1.w};
            #pragma unroll
            for (int s = 0; s < 6; ++s) {
                const float scs = sc[s];
                #pragma unroll
                for (int jj = 0; jj < 8; ++jj)
                    x[jj] = fmaf(scs, w1r[s][jj], x[jj]);
            }
            #pragma unroll
            for (int jj = 0; jj < 8; ++jj) x[jj] = gelu_fast(x[jj]);
            fa0.u.x = pack_bf16_rne(x[0], x[1]);
            fa0.u.y = pack_bf16_rne(x[2], x[3]);
            fa0.u.z = pack_bf16_rne(x[4], x[5]);
            fa0.u.w = pack_bf16_rne(x[6], x[7]);
        }
        // ks1 half: k = 32+kA.. (W1s slice via broadcast LDS reads)
        {
            const float4 p2 = *(const float4*)(Ar + 32 + kA);
            const float4 p3 = *(const float4*)(Ar + 36 + kA);
            const float4 q2 = *(const float4*)(Br + 32 + kA);
            const float4 q3 = *(const float4*)(Br + 36 + kA);
            float y[8] = {p2.x + q2.x, p2.y + q2.y, p2.z + q2.z, p2.w + q2.w,
                          p3.x + q3.x, p3.y + q3.y, p3.z + q3.z, p3.w + q3.w};
            #pragma unroll
            for (int s = 0; s < 6; ++s) {
                const float scs = sc[s];
                const float4 w0 = *(const float4*)&sW1s[s * 64 + 32 + kA];
                const float4 w1 = *(const float4*)&sW1s[s * 64 + 36 + kA];
                y[0] = fmaf(scs, w0.x, y[0]); y[1] = fmaf(scs, w0.y, y[1]);
                y[2] = fmaf(scs, w0.z, y[2]); y[3] = fmaf(scs, w0.w, y[3]);
                y[4] = fmaf(scs, w1.x, y[4]); y[5] = fmaf(scs, w1.y, y[5]);
                y[6] = fmaf(scs, w1.z, y[6]); y[7] = fmaf(scs, w1.w, y[7]);
            }
            #pragma unroll
            for (int jj = 0; jj < 8; ++jj) y[jj] = gelu_fast(y[jj]);
            fa1.u.x = pack_bf16_rne(y[0], y[1]);
            fa1.u.y = pack_bf16_rne(y[2], y[3]);
            fa1.u.z = pack_bf16_rne(y[4], y[5]);
            fa1.u.w = pack_bf16_rne(y[6], y[7]);
        }

        // h2 = h1 @ W2 on the matrix pipe (accs live natively in AGPR/VGPR)
        v4f acc0 = {b2v0, b2v0, b2v0, b2v0};
        v4f acc1 = {b2v1, b2v1, b2v1, b2v1};
        acc0 = __builtin_amdgcn_mfma_f32_16x16x32_bf16(fa0.s, f00.s, acc0, 0, 0, 0);
        acc0 = __builtin_amdgcn_mfma_f32_16x16x32_bf16(fa1.s, f01.s, acc0, 0, 0, 0);
        acc1 = __builtin_amdgcn_mfma_f32_16x16x32_bf16(fa0.s, f10.s, acc1, 0, 0, 0);
        acc1 = __builtin_amdgcn_mfma_f32_16x16x32_bf16(fa1.s, f11.s, acc1, 0, 0, 0);

        // epilogue: gelu + W3 dot (row_ror reduce -> ALL lanes) + gate + scatter
        float cres[4];
        #pragma unroll
        for (int rr = 0; rr < 4; ++rr) {
            cres[rr] = fmaf(gelu_fast(acc0[rr]), w3v0, gelu_fast(acc1[rr]) * w3v1);
            cres[rr] = row_reduce16(cres[rr]);
        }
        const int pbase = mtl * 16 + ql * 4;
        #pragma unroll
        for (int rr = 0; rr < 4; ++rr) {
            const float edge = sigmoid_(cres[rr] + b3s);
            const float fe = edge * sGate[pbase + rr];
            if (ml == 0) {
                const int pi = sI[pbase + rr], pj = sJ[pbase + rr];
                sAdj[pi * 32 + pj] = fe;
                sAdj[pj * 32 + pi] = fe;
            }
        }
    }
    __syncthreads();   // barrier 3

    // ---- coalesced tile writeback ----
    float* dst = out + (size_t)b * 1024;
    for (int idx = t; idx < 1024; idx += 256) dst[idx] = sAdj[idx];
}

extern "C" void kernel_launch(void* const* d_in, const int* in_sizes, int n_in,
                              void* d_out, int out_size, void* d_ws, size_t ws_size,
                              hipStream_t stream) {
    const float* cel   = (const float*)d_in[0];
    const float* theta = (const float*)d_in[1];
    const float* phi   = (const float*)d_in[2];
    const float* vel   = (const float*)d_in[3];
    const float* rad   = (const float*)d_in[4];
    const float* lon   = (const float*)d_in[5];
    const float* W1    = (const float*)d_in[6];
    const float* b1    = (const float*)d_in[7];
    const float* W2    = (const float*)d_in[8];
    const float* b2    = (const float*)d_in[9];
    const float* W3    = (const float*)d_in[10];
    const float* b3    = (const float*)d_in[11];
    const float* pw    = (const float*)d_in[12];
    float* out = (float*)d_out;

    const int B = in_sizes[1] / NN;  // theta is (B,N)
    edge_kernel<<<B, 256, 0, stream>>>(cel, theta, phi, vel, rad, lon,
                                       W1, b1, W2, b2, W3, b3, pw, out);
}

// Round 6
// 282.694 us; speedup vs baseline: 1.6475x; 1.0470x over previous
//
#include <hip/hip_runtime.h>
#include <math.h>

#define SS 8
#define NN 32
#define DD 64
#define NP 496   // 32*31/2
#define LDA 68   // padded row stride (floats) for sAi/sBj; 272B (16B-aligned)

typedef short v8s __attribute__((ext_vector_type(8)));   // 8 bf16 (4 VGPRs)
typedef float v4f __attribute__((ext_vector_type(4)));   // MFMA C/D frag
typedef float f2  __attribute__((ext_vector_type(2)));   // packed fp32 pair (VOP3P)

union FragU { uint4 u; v8s s; };
union Q2    { float4 q; f2 h[2]; };

static __device__ __forceinline__ f2 f2m(float a, float b) { f2 r; r.x = a; r.y = b; return r; }
static __device__ __forceinline__ f2 splat2(float s) { f2 r; r.x = s; r.y = s; return r; }
static __device__ __forceinline__ f2 pk_fma(f2 a, f2 b, f2 c) {
#if __has_builtin(__builtin_elementwise_fma)
    return __builtin_elementwise_fma(a, b, c);    // -> v_pk_fma_f32
#else
    return f2m(fmaf(a.x, b.x, c.x), fmaf(a.y, b.y, c.y));
#endif
}

__device__ __forceinline__ float wrap_pi(float d) {
    return fmaf(-6.28318530717958647692f, rintf(d * 0.15915494309189533577f), d);
}
__device__ __forceinline__ float sigmoid_(float x) {
    return 1.0f / (1.0f + __expf(-x));
}
// Packed 2-wide GELU (exact-erf via A&S 7.1.26 minimax, max err 1.5e-7).
// Polynomial part runs on v_pk_fma_f32; only rcp/exp are scalar trans ops.
__device__ __forceinline__ f2 gelu2(f2 xin) {
    f2 z = xin * splat2(0.70710678118654752440f);
#if __has_builtin(__builtin_elementwise_max)
    f2 az = __builtin_elementwise_max(z, -z);
#else
    f2 az = f2m(fabsf(z.x), fabsf(z.y));
#endif
    f2 d = pk_fma(splat2(0.3275911f), az, splat2(1.0f));
    f2 t = f2m(__builtin_amdgcn_rcpf(d.x), __builtin_amdgcn_rcpf(d.y));
    f2 p = pk_fma(t, splat2(1.061405429f), splat2(-1.453152027f));
    p = pk_fma(p, t, splat2(1.421413741f));
    p = pk_fma(p, t, splat2(-0.284496736f));
    p = pk_fma(p, t, splat2(0.254829592f));
    p = p * t;
    f2 a2 = az * az;
    f2 e = f2m(__expf(-a2.x), __expf(-a2.y));
    f2 r = pk_fma(-p, e, splat2(1.0f));            // erf(|z|) in (0,1)
    // transfer sign of z (r is positive, so OR-ing the sign bit suffices)
    unsigned int rx = __float_as_uint(r.x) | (__float_as_uint(z.x) & 0x80000000u);
    unsigned int ry = __float_as_uint(r.y) | (__float_as_uint(z.y) & 0x80000000u);
    f2 er = f2m(__uint_as_float(rx), __uint_as_float(ry));
    return xin * pk_fma(er, splat2(0.5f), splat2(0.5f));
}
// round-to-nearest-even fp32 -> bf16 pair, packed (lo = even element)
__device__ __forceinline__ unsigned int pack_bf16_rne(float x0, float x1) {
    unsigned int u0 = __float_as_uint(x0);
    unsigned int u1 = __float_as_uint(x1);
    u0 = u0 + 0x7fffu + ((u0 >> 16) & 1u);
    u1 = u1 + 0x7fffu + ((u1 >> 16) & 1u);
    return (u0 >> 16) | (u1 & 0xffff0000u);
}
// Sum across each 16-lane DPP row via row_ror 8/4/2/1 (rotation butterfly:
// every lane ends with the full row sum, direction-agnostic). VALU pipe.
__device__ __forceinline__ float row_reduce16(float x) {
    int v;
    v = __builtin_amdgcn_update_dpp(0, __float_as_int(x), 0x128, 0xf, 0xf, false);
    x += __int_as_float(v);
    v = __builtin_amdgcn_update_dpp(0, __float_as_int(x), 0x124, 0xf, 0xf, false);
    x += __int_as_float(v);
    v = __builtin_amdgcn_update_dpp(0, __float_as_int(x), 0x122, 0xf, 0xf, false);
    x += __int_as_float(v);
    v = __builtin_amdgcn_update_dpp(0, __float_as_int(x), 0x121, 0xf, 0xf, false);
    x += __int_as_float(v);
    return x;
}
__device__ __forceinline__ uint4 build_w2_frag(const float* __restrict__ W2,
                                               int kb, int col) {
    uint4 pk;
    pk.x = pack_bf16_rne(W2[(kb + 0) * 32 + col], W2[(kb + 1) * 32 + col]);
    pk.y = pack_bf16_rne(W2[(kb + 2) * 32 + col], W2[(kb + 3) * 32 + col]);
    pk.z = pack_bf16_rne(W2[(kb + 4) * 32 + col], W2[(kb + 5) * 32 + col]);
    pk.w = pack_bf16_rne(W2[(kb + 6) * 32 + col], W2[(kb + 7) * 32 + col]);
    return pk;
}

// launch_bounds(256,3): VGPR cap ~170. Live set is ~115 regs; at <=128 the HW
// still runs 4 waves/SIMD and LDS (39.4KB -> 4 blocks/CU) stays the occupancy
// cap. (256,4) forced a 64-VGPR cap -> 14MB/dispatch scratch spills (R5).
__global__ __launch_bounds__(256, 3) void edge_kernel(
    const float* __restrict__ cel,    // (B,S,N,D)
    const float* __restrict__ theta,  // (B,N)
    const float* __restrict__ phi,
    const float* __restrict__ vel,
    const float* __restrict__ rad,
    const float* __restrict__ lon,
    const float* __restrict__ W1,     // (134,64)
    const float* __restrict__ b1,     // (64)
    const float* __restrict__ W2,     // (64,32)
    const float* __restrict__ b2,     // (32)
    const float* __restrict__ W3,     // (32)
    const float* __restrict__ b3,     // (1)
    const float* __restrict__ pw,     // (6)
    float* __restrict__ out)          // (B,N,N)
{
    __shared__ __align__(16) float sAi[NN * LDA];    // fi@W1[0:64] + b1
    __shared__ __align__(16) float sBj[NN * LDA];    // fj@W1[64:128]
    __shared__ __align__(16) float sW1s[6 * 64];     // W1 rows 128..133
    __shared__ float sScal[6][512];                  // per-pair td,pd,vd,rr,ld,pr
    __shared__ float sGate[512];
    __shared__ float sTh[NN], sPh[NN], sVe[NN], sRa[NN], sLo[NN];
    __shared__ unsigned char sI[512], sJ[512];
    __shared__ float sAdj[1024];

    const int b = blockIdx.x;
    const int t = threadIdx.x;
    const int ml = t & 15;            // frag row-within-tile / C col
    const int ql = (t >> 4) & 3;      // frag k-quad / C row-quad (== lane>>4)
    const int wv = t >> 6;            // wave id
    const int kA = ql * 8;            // this lane's ks0 k-base

    // ---- B-fragments of W2 straight from global (per-thread, no LDS) ----
    FragU f00, f01, f10, f11;
    f00.u = build_w2_frag(W2, 0 * 32 + kA, 0 * 16 + ml);
    f01.u = build_w2_frag(W2, 1 * 32 + kA, 0 * 16 + ml);
    f10.u = build_w2_frag(W2, 0 * 32 + kA, 1 * 16 + ml);
    f11.u = build_w2_frag(W2, 1 * 32 + kA, 1 * 16 + ml);
    const float b2v0 = b2[ml], b2v1 = b2[16 + ml];
    const float w3v0 = W3[ml], w3v1 = W3[16 + ml];
    const float b3s  = b3[0];

    // ---- staging ----
    if (t < NN) {
        sTh[t] = theta[b * NN + t];
        sPh[t] = phi[b * NN + t];
        sVe[t] = vel[b * NN + t];
        sRa[t] = rad[b * NN + t];
        sLo[t] = lon[b * NN + t];
    }
    if (t < 31) {  // triu pair table
        int off = t * 31 - (t * (t - 1)) / 2;
        for (int j = t + 1; j < 32; ++j) {
            sI[off] = (unsigned char)t;
            sJ[off] = (unsigned char)j;
            ++off;
        }
    }
    for (int idx = t; idx < 1024; idx += 256) sAdj[idx] = 0.0f;
    for (int idx = t; idx < 384; idx += 256) sW1s[idx] = W1[128 * 64 + idx];
    __syncthreads();   // barrier 1

    // ---- per-pair scalars + gate ----
    for (int p = t; p < NP; p += 256) {
        const int i = sI[p], j = sJ[p];
        const float td = wrap_pi(sTh[i] - sTh[j]);
        const float pd = wrap_pi(sPh[i] - sPh[j]);
        const float vd = sVe[i] - sVe[j];
        const float rr = sRa[i] / (sRa[j] + 1e-8f);
        const float ld = wrap_pi(sLo[i] - sLo[j]);
        const float pr = __cosf(td) * __cosf(pd);
        sScal[0][p] = td; sScal[1][p] = pd; sScal[2][p] = vd;
        sScal[3][p] = rr; sScal[4][p] = ld; sScal[5][p] = pr;
        const float pf = fabsf(td) * pw[0] + fabsf(pd) * pw[1]
                       + fabsf(vd) * pw[2] + fabsf(rr - 1.0f) * pw[3]
                       + fabsf(ld) * pw[4] + fabsf(pr) * pw[5];
        sGate[p] = sigmoid_(pf);
    }

    // ---- phase A: node projections (packed fp32 VALU) ----
    {
        const int col = t & 63;
        const int w   = __builtin_amdgcn_readfirstlane(t >> 6);
        const float* fbase = cel + ((size_t)b * SS + (SS - 1)) * (NN * DD);
        f2 a2v[4], b2w[4];
        #pragma unroll
        for (int c = 0; c < 4; ++c) { a2v[c] = splat2(0.0f); b2w[c] = splat2(0.0f); }
        for (int k = 0; k < 64; ++k) {
            const f2 wa = splat2(W1[k * 64 + col]);
            const f2 wb = splat2(W1[(k + 64) * 64 + col]);
            #pragma unroll
            for (int c = 0; c < 4; ++c) {
                const f2 ff = f2m(fbase[(w + 4 * (2 * c)) * 64 + k],       // s_load
                                  fbase[(w + 4 * (2 * c + 1)) * 64 + k]);  // s_load
                a2v[c] = pk_fma(ff, wa, a2v[c]);
                b2w[c] = pk_fma(ff, wb, b2w[c]);
            }
        }
        const f2 b1c = splat2(b1[col]);
        #pragma unroll
        for (int c = 0; c < 4; ++c) {
            const f2 av = a2v[c] + b1c;
            sAi[(w + 4 * (2 * c)) * LDA + col]     = av.x;
            sAi[(w + 4 * (2 * c + 1)) * LDA + col] = av.y;
            sBj[(w + 4 * (2 * c)) * LDA + col]     = b2w[c].x;
            sBj[(w + 4 * (2 * c + 1)) * LDA + col] = b2w[c].y;
        }
    }
    __syncthreads();   // barrier 2

    // ---- hoist this lane's ks0 slice of W1s (48 VGPRs, round-invariant) ----
    f2 w1f[6][4];
    #pragma unroll
    for (int s = 0; s < 6; ++s) {
        Q2 u0, u1;
        u0.q = *(const float4*)&sW1s[s * 64 + kA];
        u1.q = *(const float4*)&sW1s[s * 64 + kA + 4];
        w1f[s][0] = u0.h[0]; w1f[s][1] = u0.h[1];
        w1f[s][2] = u1.h[0]; w1f[s][3] = u1.h[1];
    }

    // ---- main loop: one 16-pair m-tile per wave-round, ZERO barriers ----
    for (int r = 0; r < 8; ++r) {
        const int mtl = r * 4 + wv;
        if (mtl >= 31) break;                    // wave-uniform
        const int p = mtl * 16 + ml;
        const int i = sI[p], j = sJ[p];
        float sc[6];
        #pragma unroll
        for (int s = 0; s < 6; ++s) sc[s] = sScal[s][p];
        const float* Ar = &sAi[i * LDA];
        const float* Br = &sBj[j * LDA];

        // ks0 half: k = kA..kA+7 (W1s slice from registers, all pk math)
        FragU fa0, fa1;
        {
            Q2 P0, P1, Q0, Q1;
            P0.q = *(const float4*)(Ar + kA);
            P1.q = *(const float4*)(Ar + kA + 4);
            Q0.q = *(const float4*)(Br + kA);
            Q1.q = *(const float4*)(Br + kA + 4);
            f2 v[4] = {P0.h[0] + Q0.h[0], P0.h[1] + Q0.h[1],
                       P1.h[0] + Q1.h[0], P1.h[1] + Q1.h[1]};
            #pragma unroll
            for (int s = 0; s < 6; ++s) {
                const f2 scs = splat2(sc[s]);
                #pragma unroll
                for (int c = 0; c < 4; ++c)
                    v[c] = pk_fma(scs, w1f[s][c], v[c]);
            }
            #pragma unroll
            for (int c = 0; c < 4; ++c) v[c] = gelu2(v[c]);
            fa0.u.x = pack_bf16_rne(v[0].x, v[0].y);
            fa0.u.y = pack_bf16_rne(v[1].x, v[1].y);
            fa0.u.z = pack_bf16_rne(v[2].x, v[2].y);
            fa0.u.w = pack_bf16_rne(v[3].x, v[3].y);
        }
        // ks1 half: k = 32+kA.. (W1s slice streamed from LDS)
        {
            Q2 P2, P3, Q2v, Q3;
            P2.q  = *(const float4*)(Ar + 32 + kA);
            P3.q  = *(const float4*)(Ar + 36 + kA);
            Q2v.q = *(const float4*)(Br + 32 + kA);
            Q3.q  = *(const float4*)(Br + 36 + kA);
            f2 y[4] = {P2.h[0] + Q2v.h[0], P2.h[1] + Q2v.h[1],
                       P3.h[0] + Q3.h[0],  P3.h[1] + Q3.h[1]};
            #pragma unroll
            for (int s = 0; s < 6; ++s) {
                const f2 scs = splat2(sc[s]);
                Q2 W0, W1v;
                W0.q  = *(const float4*)&sW1s[s * 64 + 32 + kA];
                W1v.q = *(const float4*)&sW1s[s * 64 + 36 + kA];
                y[0] = pk_fma(scs, W0.h[0],  y[0]);
                y[1] = pk_fma(scs, W0.h[1],  y[1]);
                y[2] = pk_fma(scs, W1v.h[0], y[2]);
                y[3] = pk_fma(scs, W1v.h[1], y[3]);
            }
            #pragma unroll
            for (int c = 0; c < 4; ++c) y[c] = gelu2(y[c]);
            fa1.u.x = pack_bf16_rne(y[0].x, y[0].y);
            fa1.u.y = pack_bf16_rne(y[1].x, y[1].y);
            fa1.u.z = pack_bf16_rne(y[2].x, y[2].y);
            fa1.u.w = pack_bf16_rne(y[3].x, y[3].y);
        }

        // h2 = h1 @ W2 on the matrix pipe
        v4f acc0 = {b2v0, b2v0, b2v0, b2v0};
        v4f acc1 = {b2v1, b2v1, b2v1, b2v1};
        acc0 = __builtin_amdgcn_mfma_f32_16x16x32_bf16(fa0.s, f00.s, acc0, 0, 0, 0);
        acc0 = __builtin_amdgcn_mfma_f32_16x16x32_bf16(fa1.s, f01.s, acc0, 0, 0, 0);
        acc1 = __builtin_amdgcn_mfma_f32_16x16x32_bf16(fa0.s, f10.s, acc1, 0, 0, 0);
        acc1 = __builtin_amdgcn_mfma_f32_16x16x32_bf16(fa1.s, f11.s, acc1, 0, 0, 0);

        // epilogue: pk gelu + W3 dot (row_ror reduce) + gate + scatter
        float cres[4];
        #pragma unroll
        for (int rr = 0; rr < 4; ++rr) {
            const f2 g = gelu2(f2m(acc0[rr], acc1[rr]));
            cres[rr] = row_reduce16(fmaf(g.y, w3v1, g.x * w3v0));
        }
        const int pbase = mtl * 16 + ql * 4;
        #pragma unroll
        for (int rr = 0; rr < 4; ++rr) {
            const float edge = sigmoid_(cres[rr] + b3s);
            const float fe = edge * sGate[pbase + rr];
            if (ml == 0) {
                const int pi = sI[pbase + rr], pj = sJ[pbase + rr];
                sAdj[pi * 32 + pj] = fe;
                sAdj[pj * 32 + pi] = fe;
            }
        }
    }
    __syncthreads();   // barrier 3

    // ---- coalesced tile writeback ----
    float* dst = out + (size_t)b * 1024;
    for (int idx = t; idx < 1024; idx += 256) dst[idx] = sAdj[idx];
}

extern "C" void kernel_launch(void* const* d_in, const int* in_sizes, int n_in,
                              void* d_out, int out_size, void* d_ws, size_t ws_size,
                              hipStream_t stream) {
    const float* cel   = (const float*)d_in[0];
    const float* theta = (const float*)d_in[1];
    const float* phi   = (const float*)d_in[2];
    const float* vel   = (const float*)d_in[3];
    const float* rad   = (const float*)d_in[4];
    const float* lon   = (const float*)d_in[5];
    const float* W1    = (const float*)d_in[6];
    const float* b1    = (const float*)d_in[7];
    const float* W2    = (const float*)d_in[8];
    const float* b2    = (const float*)d_in[9];
    const float* W3    = (const float*)d_in[10];
    const float* b3    = (const float*)d_in[11];
    const float* pw    = (const float*)d_in[12];
    float* out = (float*)d_out;

    const int B = in_sizes[1] / NN;  // theta is (B,N)
    edge_kernel<<<B, 256, 0, stream>>>(cel, theta, phi, vel, rad, lon,
                                       W1, b1, W2, b2, W3, b3, pw, out);
}

// Round 7
// 268.824 us; speedup vs baseline: 1.7325x; 1.0516x over previous
//
#include <hip/hip_runtime.h>
#include <hip/hip_bf16.h>
#include <math.h>

#define SS 8
#define NN 32
#define DD 64
#define NP 496   // 32*31/2
#define LDA 68   // padded row stride (floats) for sAi/sBj; 272B (16B-aligned)

typedef short v8s __attribute__((ext_vector_type(8)));   // 8 bf16 (4 VGPRs)
typedef float v4f __attribute__((ext_vector_type(4)));   // MFMA C/D frag
typedef float f2  __attribute__((ext_vector_type(2)));   // packed fp32 pair (VOP3P)

union FragU { uint4 u; v8s s; };
union Q2    { float4 q; f2 h[2]; };

static __device__ __forceinline__ f2 f2m(float a, float b) { f2 r; r.x = a; r.y = b; return r; }
static __device__ __forceinline__ f2 splat2(float s) { f2 r; r.x = s; r.y = s; return r; }
static __device__ __forceinline__ f2 pk_fma(f2 a, f2 b, f2 c) {
#if __has_builtin(__builtin_elementwise_fma)
    return __builtin_elementwise_fma(a, b, c);    // -> v_pk_fma_f32
#else
    return f2m(fmaf(a.x, b.x, c.x), fmaf(a.y, b.y, c.y));
#endif
}

__device__ __forceinline__ float wrap_pi(float d) {
    return fmaf(-6.28318530717958647692f, rintf(d * 0.15915494309189533577f), d);
}
__device__ __forceinline__ float sigmoid_(float x) {
    return 1.0f / (1.0f + __expf(-x));
}
// Packed 2-wide GELU (exact-erf via A&S 7.1.26 minimax, max err 1.5e-7).
// Polynomial part runs on v_pk_fma_f32; only rcp/exp are scalar trans ops.
__device__ __forceinline__ f2 gelu2(f2 xin) {
    f2 z = xin * splat2(0.70710678118654752440f);
#if __has_builtin(__builtin_elementwise_max)
    f2 az = __builtin_elementwise_max(z, -z);
#else
    f2 az = f2m(fabsf(z.x), fabsf(z.y));
#endif
    f2 d = pk_fma(splat2(0.3275911f), az, splat2(1.0f));
    f2 t = f2m(__builtin_amdgcn_rcpf(d.x), __builtin_amdgcn_rcpf(d.y));
    f2 p = pk_fma(t, splat2(1.061405429f), splat2(-1.453152027f));
    p = pk_fma(p, t, splat2(1.421413741f));
    p = pk_fma(p, t, splat2(-0.284496736f));
    p = pk_fma(p, t, splat2(0.254829592f));
    p = p * t;
    f2 a2 = az * az;
    f2 e = f2m(__expf(-a2.x), __expf(-a2.y));
    f2 r = pk_fma(-p, e, splat2(1.0f));            // erf(|z|) in (0,1)
    unsigned int rx = __float_as_uint(r.x) | (__float_as_uint(z.x) & 0x80000000u);
    unsigned int ry = __float_as_uint(r.y) | (__float_as_uint(z.y) & 0x80000000u);
    f2 er = f2m(__uint_as_float(rx), __uint_as_float(ry));
    return xin * pk_fma(er, splat2(0.5f), splat2(0.5f));
}
// fp32 pair -> packed bf16 (RNE). HW path: v_cvt_pk_bf16_f32 on gfx950.
__device__ __forceinline__ unsigned int pack_bf16_rne(float x0, float x1) {
    union { __hip_bfloat162 h2; unsigned int u; } cv;
    float2 f; f.x = x0; f.y = x1;
    cv.h2 = __float22bfloat162_rn(f);
    return cv.u;
}
// Sum across each 16-lane DPP row via row_ror 8/4/2/1 (rotation butterfly:
// every lane ends with the full row sum, direction-agnostic). VALU pipe.
__device__ __forceinline__ float row_reduce16(float x) {
    int v;
    v = __builtin_amdgcn_update_dpp(0, __float_as_int(x), 0x128, 0xf, 0xf, false);
    x += __int_as_float(v);
    v = __builtin_amdgcn_update_dpp(0, __float_as_int(x), 0x124, 0xf, 0xf, false);
    x += __int_as_float(v);
    v = __builtin_amdgcn_update_dpp(0, __float_as_int(x), 0x122, 0xf, 0xf, false);
    x += __int_as_float(v);
    v = __builtin_amdgcn_update_dpp(0, __float_as_int(x), 0x121, 0xf, 0xf, false);
    x += __int_as_float(v);
    return x;
}
__device__ __forceinline__ uint4 build_w2_frag(const float* __restrict__ W2,
                                               int kb, int col) {
    uint4 pk;
    pk.x = pack_bf16_rne(W2[(kb + 0) * 32 + col], W2[(kb + 1) * 32 + col]);
    pk.y = pack_bf16_rne(W2[(kb + 2) * 32 + col], W2[(kb + 3) * 32 + col]);
    pk.z = pack_bf16_rne(W2[(kb + 4) * 32 + col], W2[(kb + 5) * 32 + col]);
    pk.w = pack_bf16_rne(W2[(kb + 6) * 32 + col], W2[(kb + 7) * 32 + col]);
    return pk;
}

// (256,2): unified reg budget 256/thread. R6 showed (256,3) still split 64V+64A
// (VGPR_Count=64) -> AGPR move traffic for w1f/B-frags. We are issue-bound
// (VALUBusy 62%, occupancy already ~3 blocks/CU), so trading a resident block
// for a clean allocation is the right direction.
__global__ __launch_bounds__(256, 2) void edge_kernel(
    const float* __restrict__ cel,    // (B,S,N,D)
    const float* __restrict__ theta,  // (B,N)
    const float* __restrict__ phi,
    const float* __restrict__ vel,
    const float* __restrict__ rad,
    const float* __restrict__ lon,
    const float* __restrict__ W1,     // (134,64)
    const float* __restrict__ b1,     // (64)
    const float* __restrict__ W2,     // (64,32)
    const float* __restrict__ b2,     // (32)
    const float* __restrict__ W3,     // (32)
    const float* __restrict__ b3,     // (1)
    const float* __restrict__ pw,     // (6)
    float* __restrict__ out)          // (B,N,N)
{
    __shared__ __align__(16) float sAi[NN * LDA];    // fi@W1[0:64] + b1
    __shared__ __align__(16) float sBj[NN * LDA];    // fj@W1[64:128]
    __shared__ __align__(16) float sW1s[6 * 64];     // W1 rows 128..133
    __shared__ float sScal[6][512];                  // per-pair td,pd,vd,rr,ld,pr
    __shared__ float sGate[512];
    __shared__ float sTh[NN], sPh[NN], sVe[NN], sRa[NN], sLo[NN];
    __shared__ unsigned char sI[512], sJ[512];
    __shared__ float sAdj[1024];

    const int b = blockIdx.x;
    const int t = threadIdx.x;
    const int ml = t & 15;            // frag row-within-tile / C col
    const int ql = (t >> 4) & 3;      // frag k-quad / C row-quad (== lane>>4)
    const int wv = t >> 6;            // wave id
    const int kA = ql * 8;            // this lane's ks0 k-base

    // ---- B-fragments of W2 straight from global (per-thread, no LDS) ----
    FragU f00, f01, f10, f11;
    f00.u = build_w2_frag(W2, 0 * 32 + kA, 0 * 16 + ml);
    f01.u = build_w2_frag(W2, 1 * 32 + kA, 0 * 16 + ml);
    f10.u = build_w2_frag(W2, 0 * 32 + kA, 1 * 16 + ml);
    f11.u = build_w2_frag(W2, 1 * 32 + kA, 1 * 16 + ml);
    const float b2v0 = b2[ml], b2v1 = b2[16 + ml];
    const float w3v0 = W3[ml], w3v1 = W3[16 + ml];
    const float b3s  = b3[0];

    // ---- staging ----
    if (t < NN) {
        sTh[t] = theta[b * NN + t];
        sPh[t] = phi[b * NN + t];
        sVe[t] = vel[b * NN + t];
        sRa[t] = rad[b * NN + t];
        sLo[t] = lon[b * NN + t];
    }
    if (t < 31) {  // triu pair table
        int off = t * 31 - (t * (t - 1)) / 2;
        for (int j = t + 1; j < 32; ++j) {
            sI[off] = (unsigned char)t;
            sJ[off] = (unsigned char)j;
            ++off;
        }
    }
    for (int idx = t; idx < 1024; idx += 256) sAdj[idx] = 0.0f;
    for (int idx = t; idx < 384; idx += 256) sW1s[idx] = W1[128 * 64 + idx];
    __syncthreads();   // barrier 1

    // ---- per-pair scalars + gate ----
    for (int p = t; p < NP; p += 256) {
        const int i = sI[p], j = sJ[p];
        const float td = wrap_pi(sTh[i] - sTh[j]);
        const float pd = wrap_pi(sPh[i] - sPh[j]);
        const float vd = sVe[i] - sVe[j];
        const float rr = sRa[i] / (sRa[j] + 1e-8f);
        const float ld = wrap_pi(sLo[i] - sLo[j]);
        const float pr = __cosf(td) * __cosf(pd);
        sScal[0][p] = td; sScal[1][p] = pd; sScal[2][p] = vd;
        sScal[3][p] = rr; sScal[4][p] = ld; sScal[5][p] = pr;
        const float pf = fabsf(td) * pw[0] + fabsf(pd) * pw[1]
                       + fabsf(vd) * pw[2] + fabsf(rr - 1.0f) * pw[3]
                       + fabsf(ld) * pw[4] + fabsf(pr) * pw[5];
        sGate[p] = sigmoid_(pf);
    }

    // ---- phase A: node projections (packed fp32 VALU) ----
    // feats reads are wave-uniform -> batched s_load_dwordx4; W1 reads are
    // per-lane coalesced vector loads.
    {
        const int col = t & 63;
        const int w   = __builtin_amdgcn_readfirstlane(t >> 6);
        const float* fbase = cel + ((size_t)b * SS + (SS - 1)) * (NN * DD);
        f2 a2v[4], b2w[4];
        #pragma unroll
        for (int c = 0; c < 4; ++c) { a2v[c] = splat2(0.0f); b2w[c] = splat2(0.0f); }
        for (int k4 = 0; k4 < 64; k4 += 4) {
            float4 fv[8];
            #pragma unroll
            for (int m = 0; m < 8; ++m)
                fv[m] = *(const float4*)&fbase[(w + 4 * m) * 64 + k4];  // s_load_dwordx4
            #pragma unroll
            for (int kk = 0; kk < 4; ++kk) {
                const f2 wa = splat2(W1[(k4 + kk) * 64 + col]);
                const f2 wb = splat2(W1[(k4 + kk + 64) * 64 + col]);
                #pragma unroll
                for (int c = 0; c < 4; ++c) {
                    const f2 ff = f2m(((const float*)&fv[2 * c])[kk],
                                      ((const float*)&fv[2 * c + 1])[kk]);
                    a2v[c] = pk_fma(ff, wa, a2v[c]);
                    b2w[c] = pk_fma(ff, wb, b2w[c]);
                }
            }
        }
        const f2 b1c = splat2(b1[col]);
        #pragma unroll
        for (int c = 0; c < 4; ++c) {
            const f2 av = a2v[c] + b1c;
            sAi[(w + 4 * (2 * c)) * LDA + col]     = av.x;
            sAi[(w + 4 * (2 * c + 1)) * LDA + col] = av.y;
            sBj[(w + 4 * (2 * c)) * LDA + col]     = b2w[c].x;
            sBj[(w + 4 * (2 * c + 1)) * LDA + col] = b2w[c].y;
        }
    }
    __syncthreads();   // barrier 2

    // ---- hoist this lane's ks0 slice of W1s (48 VGPRs, round-invariant) ----
    f2 w1f[6][4];
    #pragma unroll
    for (int s = 0; s < 6; ++s) {
        Q2 u0, u1;
        u0.q = *(const float4*)&sW1s[s * 64 + kA];
        u1.q = *(const float4*)&sW1s[s * 64 + kA + 4];
        w1f[s][0] = u0.h[0]; w1f[s][1] = u0.h[1];
        w1f[s][2] = u1.h[0]; w1f[s][3] = u1.h[1];
    }

    // ---- main loop: one 16-pair m-tile per wave-round, ZERO barriers ----
    for (int r = 0; r < 8; ++r) {
        const int mtl = r * 4 + wv;
        if (mtl >= 31) break;                    // wave-uniform
        const int p = mtl * 16 + ml;
        const int i = sI[p], j = sJ[p];
        float sc[6];
        #pragma unroll
        for (int s = 0; s < 6; ++s) sc[s] = sScal[s][p];
        const float* Ar = &sAi[i * LDA];
        const float* Br = &sBj[j * LDA];

        // ks0 half: k = kA..kA+7 (W1s slice from registers, all pk math)
        FragU fa0, fa1;
        {
            Q2 P0, P1, Q0, Q1;
            P0.q = *(const float4*)(Ar + kA);
            P1.q = *(const float4*)(Ar + kA + 4);
            Q0.q = *(const float4*)(Br + kA);
            Q1.q = *(const float4*)(Br + kA + 4);
            f2 v[4] = {P0.h[0] + Q0.h[0], P0.h[1] + Q0.h[1],
                       P1.h[0] + Q1.h[0], P1.h[1] + Q1.h[1]};
            #pragma unroll
            for (int s = 0; s < 6; ++s) {
                const f2 scs = splat2(sc[s]);
                #pragma unroll
                for (int c = 0; c < 4; ++c)
                    v[c] = pk_fma(scs, w1f[s][c], v[c]);
            }
            #pragma unroll
            for (int c = 0; c < 4; ++c) v[c] = gelu2(v[c]);
            fa0.u.x = pack_bf16_rne(v[0].x, v[0].y);
            fa0.u.y = pack_bf16_rne(v[1].x, v[1].y);
            fa0.u.z = pack_bf16_rne(v[2].x, v[2].y);
            fa0.u.w = pack_bf16_rne(v[3].x, v[3].y);
        }
        // ks1 half: k = 32+kA.. (W1s slice streamed from LDS)
        {
            Q2 P2, P3, Q2v, Q3;
            P2.q  = *(const float4*)(Ar + 32 + kA);
            P3.q  = *(const float4*)(Ar + 36 + kA);
            Q2v.q = *(const float4*)(Br + 32 + kA);
            Q3.q  = *(const float4*)(Br + 36 + kA);
            f2 y[4] = {P2.h[0] + Q2v.h[0], P2.h[1] + Q2v.h[1],
                       P3.h[0] + Q3.h[0],  P3.h[1] + Q3.h[1]};
            #pragma unroll
            for (int s = 0; s < 6; ++s) {
                const f2 scs = splat2(sc[s]);
                Q2 W0, W1v;
                W0.q  = *(const float4*)&sW1s[s * 64 + 32 + kA];
                W1v.q = *(const float4*)&sW1s[s * 64 + 36 + kA];
                y[0] = pk_fma(scs, W0.h[0],  y[0]);
                y[1] = pk_fma(scs, W0.h[1],  y[1]);
                y[2] = pk_fma(scs, W1v.h[0], y[2]);
                y[3] = pk_fma(scs, W1v.h[1], y[3]);
            }
            #pragma unroll
            for (int c = 0; c < 4; ++c) y[c] = gelu2(y[c]);
            fa1.u.x = pack_bf16_rne(y[0].x, y[0].y);
            fa1.u.y = pack_bf16_rne(y[1].x, y[1].y);
            fa1.u.z = pack_bf16_rne(y[2].x, y[2].y);
            fa1.u.w = pack_bf16_rne(y[3].x, y[3].y);
        }

        // h2 = h1 @ W2 on the matrix pipe
        v4f acc0 = {b2v0, b2v0, b2v0, b2v0};
        v4f acc1 = {b2v1, b2v1, b2v1, b2v1};
        acc0 = __builtin_amdgcn_mfma_f32_16x16x32_bf16(fa0.s, f00.s, acc0, 0, 0, 0);
        acc0 = __builtin_amdgcn_mfma_f32_16x16x32_bf16(fa1.s, f01.s, acc0, 0, 0, 0);
        acc1 = __builtin_amdgcn_mfma_f32_16x16x32_bf16(fa0.s, f10.s, acc1, 0, 0, 0);
        acc1 = __builtin_amdgcn_mfma_f32_16x16x32_bf16(fa1.s, f11.s, acc1, 0, 0, 0);

        // epilogue: pk gelu + W3 dot (row_ror reduce) + gate + scatter
        float cres[4];
        #pragma unroll
        for (int rr = 0; rr < 4; ++rr) {
            const f2 g = gelu2(f2m(acc0[rr], acc1[rr]));
            cres[rr] = row_reduce16(fmaf(g.y, w3v1, g.x * w3v0));
        }
        const int pbase = mtl * 16 + ql * 4;
        #pragma unroll
        for (int rr = 0; rr < 4; ++rr) {
            const float edge = sigmoid_(cres[rr] + b3s);
            const float fe = edge * sGate[pbase + rr];
            if (ml == 0) {
                const int pi = sI[pbase + rr], pj = sJ[pbase + rr];
                sAdj[pi * 32 + pj] = fe;
                sAdj[pj * 32 + pi] = fe;
            }
        }
    }
    __syncthreads();   // barrier 3

    // ---- coalesced tile writeback ----
    float* dst = out + (size_t)b * 1024;
    for (int idx = t; idx < 1024; idx += 256) dst[idx] = sAdj[idx];
}

extern "C" void kernel_launch(void* const* d_in, const int* in_sizes, int n_in,
                              void* d_out, int out_size, void* d_ws, size_t ws_size,
                              hipStream_t stream) {
    const float* cel   = (const float*)d_in[0];
    const float* theta = (const float*)d_in[1];
    const float* phi   = (const float*)d_in[2];
    const float* vel   = (const float*)d_in[3];
    const float* rad   = (const float*)d_in[4];
    const float* lon   = (const float*)d_in[5];
    const float* W1    = (const float*)d_in[6];
    const float* b1    = (const float*)d_in[7];
    const float* W2    = (const float*)d_in[8];
    const float* b2    = (const float*)d_in[9];
    const float* W3    = (const float*)d_in[10];
    const float* b3    = (const float*)d_in[11];
    const float* pw    = (const float*)d_in[12];
    float* out = (float*)d_out;

    const int B = in_sizes[1] / NN;  // theta is (B,N)
    edge_kernel<<<B, 256, 0, stream>>>(cel, theta, phi, vel, rad, lon,
                                       W1, b1, W2, b2, W3, b3, pw, out);
}

// Round 8
// 258.329 us; speedup vs baseline: 1.8029x; 1.0406x over previous
//
#include <hip/hip_runtime.h>
#include <hip/hip_bf16.h>
#include <math.h>

#define SS 8
#define NN 32
#define DD 64
#define NP 496   // 32*31/2
#define LDA 68   // padded row stride (floats) for sAi/sBj; 272B (16B-aligned)

typedef short v8s __attribute__((ext_vector_type(8)));   // 8 bf16 (4 VGPRs)
typedef float v4f __attribute__((ext_vector_type(4)));   // MFMA C/D frag
typedef float f2  __attribute__((ext_vector_type(2)));   // packed fp32 pair (VOP3P)

union FragU { uint4 u; v8s s; };
union Q2    { float4 q; f2 h[2]; };

static __device__ __forceinline__ f2 f2m(float a, float b) { f2 r; r.x = a; r.y = b; return r; }
static __device__ __forceinline__ f2 splat2(float s) { f2 r; r.x = s; r.y = s; return r; }
static __device__ __forceinline__ f2 pk_fma(f2 a, f2 b, f2 c) {
#if __has_builtin(__builtin_elementwise_fma)
    return __builtin_elementwise_fma(a, b, c);    // -> v_pk_fma_f32
#else
    return f2m(fmaf(a.x, b.x, c.x), fmaf(a.y, b.y, c.y));
#endif
}

__device__ __forceinline__ float wrap_pi(float d) {
    return fmaf(-6.28318530717958647692f, rintf(d * 0.15915494309189533577f), d);
}
// sigmoid via hw rcp (avoids the ~10-inst v_div refinement chain; 1e-7 rel err)
__device__ __forceinline__ float sigmoid_(float x) {
    return __builtin_amdgcn_rcpf(1.0f + __expf(-x));
}
// Packed 2-wide GELU, erf via A&S 7.1.27: erf(a) ~= 1 - (1+a1 a+a2 a^2+a3 a^3
// +a4 a^4)^-4, |eps|<=5e-4 — NO exp, one rcp per element (quarter-rate trans
// count per pair: 2, vs 4 for the 7.1.26 form). rcp-first => no overflow.
// 5e-4 erf error -> <1e-3 at kernel output (x0.07 W2, sigmoid' 0.25).
__device__ __forceinline__ f2 gelu2(f2 xin) {
    f2 z = xin * splat2(0.70710678118654752440f);
#if __has_builtin(__builtin_elementwise_max)
    f2 az = __builtin_elementwise_max(z, -z);
#else
    f2 az = f2m(fabsf(z.x), fabsf(z.y));
#endif
    f2 d = pk_fma(splat2(0.078108f), az, splat2(0.000972f));
    d = pk_fma(d, az, splat2(0.230389f));
    d = pk_fma(d, az, splat2(0.278393f));
    d = pk_fma(d, az, splat2(1.0f));
    f2 t = f2m(__builtin_amdgcn_rcpf(d.x), __builtin_amdgcn_rcpf(d.y));
    f2 t2 = t * t;
    f2 r = pk_fma(-t2, t2, splat2(1.0f));          // 1 - t^4 = erf(|z|)
    unsigned int rx = __float_as_uint(r.x) | (__float_as_uint(z.x) & 0x80000000u);
    unsigned int ry = __float_as_uint(r.y) | (__float_as_uint(z.y) & 0x80000000u);
    f2 er = f2m(__uint_as_float(rx), __uint_as_float(ry));
    return xin * pk_fma(er, splat2(0.5f), splat2(0.5f));
}
// fp32 pair -> packed bf16 (RNE). HW path: v_cvt_pk_bf16_f32 on gfx950.
__device__ __forceinline__ unsigned int pack_bf16_rne(float x0, float x1) {
    union { __hip_bfloat162 h2; unsigned int u; } cv;
    float2 f; f.x = x0; f.y = x1;
    cv.h2 = __float22bfloat162_rn(f);
    return cv.u;
}
// Sum across each 16-lane DPP row via row_ror 8/4/2/1 (rotation butterfly:
// every lane ends with the full row sum, direction-agnostic). VALU pipe.
__device__ __forceinline__ float row_reduce16(float x) {
    int v;
    v = __builtin_amdgcn_update_dpp(0, __float_as_int(x), 0x128, 0xf, 0xf, false);
    x += __int_as_float(v);
    v = __builtin_amdgcn_update_dpp(0, __float_as_int(x), 0x124, 0xf, 0xf, false);
    x += __int_as_float(v);
    v = __builtin_amdgcn_update_dpp(0, __float_as_int(x), 0x122, 0xf, 0xf, false);
    x += __int_as_float(v);
    v = __builtin_amdgcn_update_dpp(0, __float_as_int(x), 0x121, 0xf, 0xf, false);
    x += __int_as_float(v);
    return x;
}
__device__ __forceinline__ uint4 build_w2_frag(const float* __restrict__ W2,
                                               int kb, int col) {
    uint4 pk;
    pk.x = pack_bf16_rne(W2[(kb + 0) * 32 + col], W2[(kb + 1) * 32 + col]);
    pk.y = pack_bf16_rne(W2[(kb + 2) * 32 + col], W2[(kb + 3) * 32 + col]);
    pk.z = pack_bf16_rne(W2[(kb + 4) * 32 + col], W2[(kb + 5) * 32 + col]);
    pk.w = pack_bf16_rne(W2[(kb + 6) * 32 + col], W2[(kb + 7) * 32 + col]);
    return pk;
}

__global__ __launch_bounds__(256, 2) void edge_kernel(
    const float* __restrict__ cel,    // (B,S,N,D)
    const float* __restrict__ theta,  // (B,N)
    const float* __restrict__ phi,
    const float* __restrict__ vel,
    const float* __restrict__ rad,
    const float* __restrict__ lon,
    const float* __restrict__ W1,     // (134,64)
    const float* __restrict__ b1,     // (64)
    const float* __restrict__ W2,     // (64,32)
    const float* __restrict__ b2,     // (32)
    const float* __restrict__ W3,     // (32)
    const float* __restrict__ b3,     // (1)
    const float* __restrict__ pw,     // (6)
    float* __restrict__ out)          // (B,N,N)
{
    __shared__ __align__(16) float sAi[NN * LDA];    // fi@W1[0:64] + b1
    __shared__ __align__(16) float sBj[NN * LDA];    // fj@W1[64:128]
    __shared__ __align__(16) float sW1s[6 * 64];     // W1 rows 128..133
    __shared__ float sScal[6][512];                  // per-pair td,pd,vd,rr,ld,pr
    __shared__ float sGate[512];
    __shared__ float sTh[NN], sPh[NN], sVe[NN], sRa[NN], sLo[NN];
    __shared__ unsigned char sI[512], sJ[512];
    __shared__ float sAdj[1024];

    const int b = blockIdx.x;
    const int t = threadIdx.x;
    const int ml = t & 15;            // frag row-within-tile / C col
    const int ql = (t >> 4) & 3;      // frag k-quad / C row-quad (== lane>>4)
    const int wv = t >> 6;            // wave id
    const int kA = ql * 8;            // this lane's ks0 k-base

    // ---- B-fragments of W2 straight from global (per-thread, no LDS) ----
    FragU f00, f01, f10, f11;
    f00.u = build_w2_frag(W2, 0 * 32 + kA, 0 * 16 + ml);
    f01.u = build_w2_frag(W2, 1 * 32 + kA, 0 * 16 + ml);
    f10.u = build_w2_frag(W2, 0 * 32 + kA, 1 * 16 + ml);
    f11.u = build_w2_frag(W2, 1 * 32 + kA, 1 * 16 + ml);
    const float b2v0 = b2[ml], b2v1 = b2[16 + ml];
    const float w3v0 = W3[ml], w3v1 = W3[16 + ml];
    const float b3s  = b3[0];

    // ---- staging ----
    if (t < NN) {
        sTh[t] = theta[b * NN + t];
        sPh[t] = phi[b * NN + t];
        sVe[t] = vel[b * NN + t];
        sRa[t] = rad[b * NN + t];
        sLo[t] = lon[b * NN + t];
    }
    if (t < 31) {  // triu pair table
        int off = t * 31 - (t * (t - 1)) / 2;
        for (int j = t + 1; j < 32; ++j) {
            sI[off] = (unsigned char)t;
            sJ[off] = (unsigned char)j;
            ++off;
        }
    }
    for (int idx = t; idx < 1024; idx += 256) sAdj[idx] = 0.0f;
    for (int idx = t; idx < 384; idx += 256) sW1s[idx] = W1[128 * 64 + idx];
    __syncthreads();   // barrier 1

    // ---- per-pair scalars + gate ----
    for (int p = t; p < NP; p += 256) {
        const int i = sI[p], j = sJ[p];
        const float td = wrap_pi(sTh[i] - sTh[j]);
        const float pd = wrap_pi(sPh[i] - sPh[j]);
        const float vd = sVe[i] - sVe[j];
        const float rr = sRa[i] * __builtin_amdgcn_rcpf(sRa[j] + 1e-8f);
        const float ld = wrap_pi(sLo[i] - sLo[j]);
        const float pr = __cosf(td) * __cosf(pd);
        sScal[0][p] = td; sScal[1][p] = pd; sScal[2][p] = vd;
        sScal[3][p] = rr; sScal[4][p] = ld; sScal[5][p] = pr;
        const float pf = fabsf(td) * pw[0] + fabsf(pd) * pw[1]
                       + fabsf(vd) * pw[2] + fabsf(rr - 1.0f) * pw[3]
                       + fabsf(ld) * pw[4] + fabsf(pr) * pw[5];
        sGate[p] = sigmoid_(pf);
    }

    // ---- phase A: node projections (packed fp32 VALU) ----
    // Packed halves = (even k, odd k) partial sums, so the feats operand of
    // each pk_fma is an ADJACENT sgpr pair straight out of s_load_dwordx4
    // (legal single-sgpr-pair VOP3P operand -> no v_mov assembly); weights
    // are per-lane coalesced vector loads paired likewise.
    {
        const int col = t & 63;
        const int w   = __builtin_amdgcn_readfirstlane(t >> 6);
        const float* fbase = cel + ((size_t)b * SS + (SS - 1)) * (NN * DD);
        f2 accA[8], accB[8];
        #pragma unroll
        for (int m = 0; m < 8; ++m) { accA[m] = splat2(0.0f); accB[m] = splat2(0.0f); }
        for (int k4 = 0; k4 < 64; k4 += 4) {
            const f2 wa01 = f2m(W1[(k4 + 0) * 64 + col], W1[(k4 + 1) * 64 + col]);
            const f2 wa23 = f2m(W1[(k4 + 2) * 64 + col], W1[(k4 + 3) * 64 + col]);
            const f2 wb01 = f2m(W1[(k4 + 64) * 64 + col], W1[(k4 + 65) * 64 + col]);
            const f2 wb23 = f2m(W1[(k4 + 66) * 64 + col], W1[(k4 + 67) * 64 + col]);
            #pragma unroll
            for (int m = 0; m < 8; ++m) {
                const float4 fv = *(const float4*)&fbase[(w + 4 * m) * 64 + k4]; // s_load_dwordx4
                accA[m] = pk_fma(f2m(fv.x, fv.y), wa01, accA[m]);
                accA[m] = pk_fma(f2m(fv.z, fv.w), wa23, accA[m]);
                accB[m] = pk_fma(f2m(fv.x, fv.y), wb01, accB[m]);
                accB[m] = pk_fma(f2m(fv.z, fv.w), wb23, accB[m]);
            }
        }
        const float b1c = b1[col];
        #pragma unroll
        for (int m = 0; m < 8; ++m) {
            sAi[(w + 4 * m) * LDA + col] = accA[m].x + accA[m].y + b1c;
            sBj[(w + 4 * m) * LDA + col] = accB[m].x + accB[m].y;
        }
    }
    __syncthreads();   // barrier 2

    // ---- hoist this lane's ks0 slice of W1s (48 VGPRs, round-invariant) ----
    f2 w1f[6][4];
    #pragma unroll
    for (int s = 0; s < 6; ++s) {
        Q2 u0, u1;
        u0.q = *(const float4*)&sW1s[s * 64 + kA];
        u1.q = *(const float4*)&sW1s[s * 64 + kA + 4];
        w1f[s][0] = u0.h[0]; w1f[s][1] = u0.h[1];
        w1f[s][2] = u1.h[0]; w1f[s][3] = u1.h[1];
    }

    // ---- main loop: one 16-pair m-tile per wave-round, ZERO barriers ----
    for (int r = 0; r < 8; ++r) {
        const int mtl = r * 4 + wv;
        if (mtl >= 31) break;                    // wave-uniform
        const int p = mtl * 16 + ml;
        const int i = sI[p], j = sJ[p];
        float sc[6];
        #pragma unroll
        for (int s = 0; s < 6; ++s) sc[s] = sScal[s][p];
        const float* Ar = &sAi[i * LDA];
        const float* Br = &sBj[j * LDA];

        // ks0 half: k = kA..kA+7 (W1s slice from registers, all pk math)
        FragU fa0, fa1;
        {
            Q2 P0, P1, Q0, Q1;
            P0.q = *(const float4*)(Ar + kA);
            P1.q = *(const float4*)(Ar + kA + 4);
            Q0.q = *(const float4*)(Br + kA);
            Q1.q = *(const float4*)(Br + kA + 4);
            f2 v[4] = {P0.h[0] + Q0.h[0], P0.h[1] + Q0.h[1],
                       P1.h[0] + Q1.h[0], P1.h[1] + Q1.h[1]};
            #pragma unroll
            for (int s = 0; s < 6; ++s) {
                const f2 scs = splat2(sc[s]);
                #pragma unroll
                for (int c = 0; c < 4; ++c)
                    v[c] = pk_fma(scs, w1f[s][c], v[c]);
            }
            #pragma unroll
            for (int c = 0; c < 4; ++c) v[c] = gelu2(v[c]);
            fa0.u.x = pack_bf16_rne(v[0].x, v[0].y);
            fa0.u.y = pack_bf16_rne(v[1].x, v[1].y);
            fa0.u.z = pack_bf16_rne(v[2].x, v[2].y);
            fa0.u.w = pack_bf16_rne(v[3].x, v[3].y);
        }
        // ks1 half: k = 32+kA.. (W1s slice streamed from LDS)
        {
            Q2 P2, P3, Q2v, Q3;
            P2.q  = *(const float4*)(Ar + 32 + kA);
            P3.q  = *(const float4*)(Ar + 36 + kA);
            Q2v.q = *(const float4*)(Br + 32 + kA);
            Q3.q  = *(const float4*)(Br + 36 + kA);
            f2 y[4] = {P2.h[0] + Q2v.h[0], P2.h[1] + Q2v.h[1],
                       P3.h[0] + Q3.h[0],  P3.h[1] + Q3.h[1]};
            #pragma unroll
            for (int s = 0; s < 6; ++s) {
                const f2 scs = splat2(sc[s]);
                Q2 W0, W1v;
                W0.q  = *(const float4*)&sW1s[s * 64 + 32 + kA];
                W1v.q = *(const float4*)&sW1s[s * 64 + 36 + kA];
                y[0] = pk_fma(scs, W0.h[0],  y[0]);
                y[1] = pk_fma(scs, W0.h[1],  y[1]);
                y[2] = pk_fma(scs, W1v.h[0], y[2]);
                y[3] = pk_fma(scs, W1v.h[1], y[3]);
            }
            #pragma unroll
            for (int c = 0; c < 4; ++c) y[c] = gelu2(y[c]);
            fa1.u.x = pack_bf16_rne(y[0].x, y[0].y);
            fa1.u.y = pack_bf16_rne(y[1].x, y[1].y);
            fa1.u.z = pack_bf16_rne(y[2].x, y[2].y);
            fa1.u.w = pack_bf16_rne(y[3].x, y[3].y);
        }

        // h2 = h1 @ W2 on the matrix pipe
        v4f acc0 = {b2v0, b2v0, b2v0, b2v0};
        v4f acc1 = {b2v1, b2v1, b2v1, b2v1};
        acc0 = __builtin_amdgcn_mfma_f32_16x16x32_bf16(fa0.s, f00.s, acc0, 0, 0, 0);
        acc0 = __builtin_amdgcn_mfma_f32_16x16x32_bf16(fa1.s, f01.s, acc0, 0, 0, 0);
        acc1 = __builtin_amdgcn_mfma_f32_16x16x32_bf16(fa0.s, f10.s, acc1, 0, 0, 0);
        acc1 = __builtin_amdgcn_mfma_f32_16x16x32_bf16(fa1.s, f11.s, acc1, 0, 0, 0);

        // epilogue: pk gelu + W3 dot (row_ror reduce) + gate + scatter
        float cres[4];
        #pragma unroll
        for (int rr = 0; rr < 4; ++rr) {
            const f2 g = gelu2(f2m(acc0[rr], acc1[rr]));
            cres[rr] = row_reduce16(fmaf(g.y, w3v1, g.x * w3v0));
        }
        const int pbase = mtl * 16 + ql * 4;
        #pragma unroll
        for (int rr = 0; rr < 4; ++rr) {
            const float edge = sigmoid_(cres[rr] + b3s);
            const float fe = edge * sGate[pbase + rr];
            if (ml == 0) {
                const int pi = sI[pbase + rr], pj = sJ[pbase + rr];
                sAdj[pi * 32 + pj] = fe;
                sAdj[pj * 32 + pi] = fe;
            }
        }
    }
    __syncthreads();   // barrier 3

    // ---- coalesced tile writeback ----
    float* dst = out + (size_t)b * 1024;
    for (int idx = t; idx < 1024; idx += 256) dst[idx] = sAdj[idx];
}

extern "C" void kernel_launch(void* const* d_in, const int* in_sizes, int n_in,
                              void* d_out, int out_size, void* d_ws, size_t ws_size,
                              hipStream_t stream) {
    const float* cel   = (const float*)d_in[0];
    const float* theta = (const float*)d_in[1];
    const float* phi   = (const float*)d_in[2];
    const float* vel   = (const float*)d_in[3];
    const float* rad   = (const float*)d_in[4];
    const float* lon   = (const float*)d_in[5];
    const float* W1    = (const float*)d_in[6];
    const float* b1    = (const float*)d_in[7];
    const float* W2    = (const float*)d_in[8];
    const float* b2    = (const float*)d_in[9];
    const float* W3    = (const float*)d_in[10];
    const float* b3    = (const float*)d_in[11];
    const float* pw    = (const float*)d_in[12];
    float* out = (float*)d_out;

    const int B = in_sizes[1] / NN;  // theta is (B,N)
    edge_kernel<<<B, 256, 0, stream>>>(cel, theta, phi, vel, rad, lon,
                                       W1, b1, W2, b2, W3, b3, pw, out);
}

// Round 9
// 256.892 us; speedup vs baseline: 1.8130x; 1.0056x over previous
//
#include <hip/hip_runtime.h>
#include <hip/hip_bf16.h>
#include <math.h>

#define SS 8
#define NN 32
#define DD 64
#define NP 496   // 32*31/2
#define LDA 68   // padded row stride (floats) for sAi/sBj; 272B (16B-aligned)

typedef short v8s __attribute__((ext_vector_type(8)));   // 8 bf16 (4 VGPRs)
typedef float v4f __attribute__((ext_vector_type(4)));   // MFMA C/D frag
typedef float f2  __attribute__((ext_vector_type(2)));   // packed fp32 pair (VOP3P)

union FragU { uint4 u; v8s s; };
union Q2    { float4 q; f2 h[2]; };

static __device__ __forceinline__ f2 f2m(float a, float b) { f2 r; r.x = a; r.y = b; return r; }
static __device__ __forceinline__ f2 splat2(float s) { f2 r; r.x = s; r.y = s; return r; }
static __device__ __forceinline__ f2 pk_fma(f2 a, f2 b, f2 c) {
#if __has_builtin(__builtin_elementwise_fma)
    return __builtin_elementwise_fma(a, b, c);    // -> v_pk_fma_f32
#else
    return f2m(fmaf(a.x, b.x, c.x), fmaf(a.y, b.y, c.y));
#endif
}

__device__ __forceinline__ float wrap_pi(float d) {
    return fmaf(-6.28318530717958647692f, rintf(d * 0.15915494309189533577f), d);
}
// sigmoid via hw rcp (avoids the ~10-inst v_div refinement chain; 1e-7 rel err)
__device__ __forceinline__ float sigmoid_(float x) {
    return __builtin_amdgcn_rcpf(1.0f + __expf(-x));
}
// Packed 2-wide GELU, erf via A&S 7.1.27 (|eps|<=5e-4, no exp, 1 rcp/element).
__device__ __forceinline__ f2 gelu2(f2 xin) {
    f2 z = xin * splat2(0.70710678118654752440f);
#if __has_builtin(__builtin_elementwise_max)
    f2 az = __builtin_elementwise_max(z, -z);
#else
    f2 az = f2m(fabsf(z.x), fabsf(z.y));
#endif
    f2 d = pk_fma(splat2(0.078108f), az, splat2(0.000972f));
    d = pk_fma(d, az, splat2(0.230389f));
    d = pk_fma(d, az, splat2(0.278393f));
    d = pk_fma(d, az, splat2(1.0f));
    f2 t = f2m(__builtin_amdgcn_rcpf(d.x), __builtin_amdgcn_rcpf(d.y));
    f2 t2 = t * t;
    f2 r = pk_fma(-t2, t2, splat2(1.0f));          // 1 - t^4 = erf(|z|)
    unsigned int rx = __float_as_uint(r.x) | (__float_as_uint(z.x) & 0x80000000u);
    unsigned int ry = __float_as_uint(r.y) | (__float_as_uint(z.y) & 0x80000000u);
    f2 er = f2m(__uint_as_float(rx), __uint_as_float(ry));
    return xin * pk_fma(er, splat2(0.5f), splat2(0.5f));
}
// fp32 pair -> packed bf16 (RNE). HW path: v_cvt_pk_bf16_f32 on gfx950.
__device__ __forceinline__ unsigned int pack_bf16_rne(float x0, float x1) {
    union { __hip_bfloat162 h2; unsigned int u; } cv;
    float2 f; f.x = x0; f.y = x1;
    cv.h2 = __float22bfloat162_rn(f);
    return cv.u;
}
// Sum across each 16-lane DPP row via row_ror 8/4/2/1 (rotation butterfly:
// every lane ends with the full row sum, direction-agnostic). VALU pipe.
__device__ __forceinline__ float row_reduce16(float x) {
    int v;
    v = __builtin_amdgcn_update_dpp(0, __float_as_int(x), 0x128, 0xf, 0xf, false);
    x += __int_as_float(v);
    v = __builtin_amdgcn_update_dpp(0, __float_as_int(x), 0x124, 0xf, 0xf, false);
    x += __int_as_float(v);
    v = __builtin_amdgcn_update_dpp(0, __float_as_int(x), 0x122, 0xf, 0xf, false);
    x += __int_as_float(v);
    v = __builtin_amdgcn_update_dpp(0, __float_as_int(x), 0x121, 0xf, 0xf, false);
    x += __int_as_float(v);
    return x;
}
__device__ __forceinline__ uint4 build_w2_frag(const float* __restrict__ W2,
                                               int kb, int col) {
    uint4 pk;
    pk.x = pack_bf16_rne(W2[(kb + 0) * 32 + col], W2[(kb + 1) * 32 + col]);
    pk.y = pack_bf16_rne(W2[(kb + 2) * 32 + col], W2[(kb + 3) * 32 + col]);
    pk.z = pack_bf16_rne(W2[(kb + 4) * 32 + col], W2[(kb + 5) * 32 + col]);
    pk.w = pack_bf16_rne(W2[(kb + 6) * 32 + col], W2[(kb + 7) * 32 + col]);
    return pk;
}

__global__ __launch_bounds__(256, 2) void edge_kernel(
    const float* __restrict__ cel,    // (B,S,N,D)
    const float* __restrict__ theta,  // (B,N)
    const float* __restrict__ phi,
    const float* __restrict__ vel,
    const float* __restrict__ rad,
    const float* __restrict__ lon,
    const float* __restrict__ W1,     // (134,64)
    const float* __restrict__ b1,     // (64)
    const float* __restrict__ W2,     // (64,32)
    const float* __restrict__ b2,     // (32)
    const float* __restrict__ W3,     // (32)
    const float* __restrict__ b3,     // (1)
    const float* __restrict__ pw,     // (6)
    float* __restrict__ out)          // (B,N,N)
{
    __shared__ __align__(16) float sAi[NN * LDA];    // fi@W1[0:64] + b1
    __shared__ __align__(16) float sBj[NN * LDA];    // fj@W1[64:128]
    __shared__ __align__(16) float sW1s[6 * 64];     // W1 rows 128..133
    __shared__ float sScal[6][512];                  // per-pair td,pd,vd,rr,ld,pr
    __shared__ float sGate[512];
    __shared__ float sTh[NN], sPh[NN], sVe[NN], sRa[NN], sLo[NN];
    __shared__ unsigned char sI[512], sJ[512];
    __shared__ float sAdj[1024];

    const int b = blockIdx.x;
    const int t = threadIdx.x;
    const int ml = t & 15;            // frag row-within-tile / C col
    const int ql = (t >> 4) & 3;      // frag k-quad / C row-quad (== lane>>4)
    const int wv = t >> 6;            // wave id
    const int kA = ql * 8;            // this lane's ks0 k-base

    // ---- B-fragments of W2 straight from global (per-thread, no LDS) ----
    FragU f00, f01, f10, f11;
    f00.u = build_w2_frag(W2, 0 * 32 + kA, 0 * 16 + ml);
    f01.u = build_w2_frag(W2, 1 * 32 + kA, 0 * 16 + ml);
    f10.u = build_w2_frag(W2, 0 * 32 + kA, 1 * 16 + ml);
    f11.u = build_w2_frag(W2, 1 * 32 + kA, 1 * 16 + ml);
    const float b2v0 = b2[ml], b2v1 = b2[16 + ml];
    const float w3v0 = W3[ml], w3v1 = W3[16 + ml];
    const float b3s  = b3[0];

    // ---- staging ----
    if (t < NN) {
        sTh[t] = theta[b * NN + t];
        sPh[t] = phi[b * NN + t];
        sVe[t] = vel[b * NN + t];
        sRa[t] = rad[b * NN + t];
        sLo[t] = lon[b * NN + t];
    }
    if (t < 31) {  // triu pair table
        int off = t * 31 - (t * (t - 1)) / 2;
        for (int j = t + 1; j < 32; ++j) {
            sI[off] = (unsigned char)t;
            sJ[off] = (unsigned char)j;
            ++off;
        }
    }
    for (int idx = t; idx < 1024; idx += 256) sAdj[idx] = 0.0f;
    for (int idx = t; idx < 384; idx += 256) sW1s[idx] = W1[128 * 64 + idx];
    __syncthreads();   // barrier 1

    // ---- per-pair scalars + gate ----
    for (int p = t; p < NP; p += 256) {
        const int i = sI[p], j = sJ[p];
        const float td = wrap_pi(sTh[i] - sTh[j]);
        const float pd = wrap_pi(sPh[i] - sPh[j]);
        const float vd = sVe[i] - sVe[j];
        const float rr = sRa[i] * __builtin_amdgcn_rcpf(sRa[j] + 1e-8f);
        const float ld = wrap_pi(sLo[i] - sLo[j]);
        const float pr = __cosf(td) * __cosf(pd);
        sScal[0][p] = td; sScal[1][p] = pd; sScal[2][p] = vd;
        sScal[3][p] = rr; sScal[4][p] = ld; sScal[5][p] = pr;
        const float pf = fabsf(td) * pw[0] + fabsf(pd) * pw[1]
                       + fabsf(vd) * pw[2] + fabsf(rr - 1.0f) * pw[3]
                       + fabsf(ld) * pw[4] + fabsf(pr) * pw[5];
        sGate[p] = sigmoid_(pf);
    }

    // ---- phase A: node projections (packed fp32 VALU) ----
    {
        const int col = t & 63;
        const int w   = __builtin_amdgcn_readfirstlane(t >> 6);
        const float* fbase = cel + ((size_t)b * SS + (SS - 1)) * (NN * DD);
        f2 accA[8], accB[8];
        #pragma unroll
        for (int m = 0; m < 8; ++m) { accA[m] = splat2(0.0f); accB[m] = splat2(0.0f); }
        for (int k4 = 0; k4 < 64; k4 += 4) {
            const f2 wa01 = f2m(W1[(k4 + 0) * 64 + col], W1[(k4 + 1) * 64 + col]);
            const f2 wa23 = f2m(W1[(k4 + 2) * 64 + col], W1[(k4 + 3) * 64 + col]);
            const f2 wb01 = f2m(W1[(k4 + 64) * 64 + col], W1[(k4 + 65) * 64 + col]);
            const f2 wb23 = f2m(W1[(k4 + 66) * 64 + col], W1[(k4 + 67) * 64 + col]);
            #pragma unroll
            for (int m = 0; m < 8; ++m) {
                const float4 fv = *(const float4*)&fbase[(w + 4 * m) * 64 + k4]; // s_load_dwordx4
                accA[m] = pk_fma(f2m(fv.x, fv.y), wa01, accA[m]);
                accA[m] = pk_fma(f2m(fv.z, fv.w), wa23, accA[m]);
                accB[m] = pk_fma(f2m(fv.x, fv.y), wb01, accB[m]);
                accB[m] = pk_fma(f2m(fv.z, fv.w), wb23, accB[m]);
            }
        }
        const float b1c = b1[col];
        #pragma unroll
        for (int m = 0; m < 8; ++m) {
            sAi[(w + 4 * m) * LDA + col] = accA[m].x + accA[m].y + b1c;
            sBj[(w + 4 * m) * LDA + col] = accB[m].x + accB[m].y;
        }
    }
    __syncthreads();   // barrier 2

    // ---- main loop: one 16-pair m-tile per wave-round, ZERO barriers ----
    // W1s slices are re-read from LDS every round (both halves) ON PURPOSE:
    // hoisting them (R8's w1f[6][4]) costs 48 unified regs -> >128/thread ->
    // only 3 waves/SIMD. De-hoisted, the live set fits 4 waves/SIMD; the
    // extra 12 broadcast ds_read_b128/round ride the underloaded LDS pipe.
    #pragma clang loop unroll(disable)
    for (int r = 0; r < 8; ++r) {
        const int mtl = r * 4 + wv;
        if (mtl >= 31) break;                    // wave-uniform
        const int p = mtl * 16 + ml;
        const int i = sI[p], j = sJ[p];
        float sc[6];
        #pragma unroll
        for (int s = 0; s < 6; ++s) sc[s] = sScal[s][p];
        const float* Ar = &sAi[i * LDA];
        const float* Br = &sBj[j * LDA];

        // ks0 half: k = kA..kA+7 (W1s from LDS)
        FragU fa0, fa1;
        {
            Q2 P0, P1, Q0, Q1;
            P0.q = *(const float4*)(Ar + kA);
            P1.q = *(const float4*)(Ar + kA + 4);
            Q0.q = *(const float4*)(Br + kA);
            Q1.q = *(const float4*)(Br + kA + 4);
            f2 v[4] = {P0.h[0] + Q0.h[0], P0.h[1] + Q0.h[1],
                       P1.h[0] + Q1.h[0], P1.h[1] + Q1.h[1]};
            #pragma unroll
            for (int s = 0; s < 6; ++s) {
                const f2 scs = splat2(sc[s]);
                Q2 W0, W1v;
                W0.q  = *(const float4*)&sW1s[s * 64 + kA];
                W1v.q = *(const float4*)&sW1s[s * 64 + kA + 4];
                v[0] = pk_fma(scs, W0.h[0],  v[0]);
                v[1] = pk_fma(scs, W0.h[1],  v[1]);
                v[2] = pk_fma(scs, W1v.h[0], v[2]);
                v[3] = pk_fma(scs, W1v.h[1], v[3]);
            }
            #pragma unroll
            for (int c = 0; c < 4; ++c) v[c] = gelu2(v[c]);
            fa0.u.x = pack_bf16_rne(v[0].x, v[0].y);
            fa0.u.y = pack_bf16_rne(v[1].x, v[1].y);
            fa0.u.z = pack_bf16_rne(v[2].x, v[2].y);
            fa0.u.w = pack_bf16_rne(v[3].x, v[3].y);
        }
        // ks1 half: k = 32+kA.. (W1s from LDS)
        {
            Q2 P2, P3, Q2v, Q3;
            P2.q  = *(const float4*)(Ar + 32 + kA);
            P3.q  = *(const float4*)(Ar + 36 + kA);
            Q2v.q = *(const float4*)(Br + 32 + kA);
            Q3.q  = *(const float4*)(Br + 36 + kA);
            f2 y[4] = {P2.h[0] + Q2v.h[0], P2.h[1] + Q2v.h[1],
                       P3.h[0] + Q3.h[0],  P3.h[1] + Q3.h[1]};
            #pragma unroll
            for (int s = 0; s < 6; ++s) {
                const f2 scs = splat2(sc[s]);
                Q2 W0, W1v;
                W0.q  = *(const float4*)&sW1s[s * 64 + 32 + kA];
                W1v.q = *(const float4*)&sW1s[s * 64 + 36 + kA];
                y[0] = pk_fma(scs, W0.h[0],  y[0]);
                y[1] = pk_fma(scs, W0.h[1],  y[1]);
                y[2] = pk_fma(scs, W1v.h[0], y[2]);
                y[3] = pk_fma(scs, W1v.h[1], y[3]);
            }
            #pragma unroll
            for (int c = 0; c < 4; ++c) y[c] = gelu2(y[c]);
            fa1.u.x = pack_bf16_rne(y[0].x, y[0].y);
            fa1.u.y = pack_bf16_rne(y[1].x, y[1].y);
            fa1.u.z = pack_bf16_rne(y[2].x, y[2].y);
            fa1.u.w = pack_bf16_rne(y[3].x, y[3].y);
        }

        // h2 = h1 @ W2 on the matrix pipe
        v4f acc0 = {b2v0, b2v0, b2v0, b2v0};
        v4f acc1 = {b2v1, b2v1, b2v1, b2v1};
        acc0 = __builtin_amdgcn_mfma_f32_16x16x32_bf16(fa0.s, f00.s, acc0, 0, 0, 0);
        acc0 = __builtin_amdgcn_mfma_f32_16x16x32_bf16(fa1.s, f01.s, acc0, 0, 0, 0);
        acc1 = __builtin_amdgcn_mfma_f32_16x16x32_bf16(fa0.s, f10.s, acc1, 0, 0, 0);
        acc1 = __builtin_amdgcn_mfma_f32_16x16x32_bf16(fa1.s, f11.s, acc1, 0, 0, 0);

        // epilogue: pk gelu + W3 dot (row_ror reduce leaves the sum in EVERY
        // lane) -> lane rsel=ml&3 selects its pair -> ONE sigmoid/gate for
        // the whole tile (was 4x) -> lanes ml<4 scatter.
        float cres[4];
        #pragma unroll
        for (int rr = 0; rr < 4; ++rr) {
            const f2 g = gelu2(f2m(acc0[rr], acc1[rr]));
            cres[rr] = row_reduce16(fmaf(g.y, w3v1, g.x * w3v0));
        }
        const int rsel = ml & 3;     // constant-index ternary: no scratch
        const float cs = (rsel & 2) ? ((rsel & 1) ? cres[3] : cres[2])
                                    : ((rsel & 1) ? cres[1] : cres[0]);
        const int pe = mtl * 16 + ql * 4 + rsel;
        const float fe = sigmoid_(cs + b3s) * sGate[pe];
        if (ml < 4) {
            const int pi = sI[pe], pj = sJ[pe];
            sAdj[pi * 32 + pj] = fe;
            sAdj[pj * 32 + pi] = fe;
        }
    }
    __syncthreads();   // barrier 3

    // ---- coalesced tile writeback ----
    float* dst = out + (size_t)b * 1024;
    for (int idx = t; idx < 1024; idx += 256) dst[idx] = sAdj[idx];
}

extern "C" void kernel_launch(void* const* d_in, const int* in_sizes, int n_in,
                              void* d_out, int out_size, void* d_ws, size_t ws_size,
                              hipStream_t stream) {
    const float* cel   = (const float*)d_in[0];
    const float* theta = (const float*)d_in[1];
    const float* phi   = (const float*)d_in[2];
    const float* vel   = (const float*)d_in[3];
    const float* rad   = (const float*)d_in[4];
    const float* lon   = (const float*)d_in[5];
    const float* W1    = (const float*)d_in[6];
    const float* b1    = (const float*)d_in[7];
    const float* W2    = (const float*)d_in[8];
    const float* b2    = (const float*)d_in[9];
    const float* W3    = (const float*)d_in[10];
    const float* b3    = (const float*)d_in[11];
    const float* pw    = (const float*)d_in[12];
    float* out = (float*)d_out;

    const int B = in_sizes[1] / NN;  // theta is (B,N)
    edge_kernel<<<B, 256, 0, stream>>>(cel, theta, phi, vel, rad, lon,
                                       W1, b1, W2, b2, W3, b3, pw, out);
}